// Round 1
// baseline (1165.819 us; speedup 1.0000x reference)
//
#include <hip/hip_runtime.h>
#include <hip/hip_bf16.h>

// Sizes (match reference)
#define BB 4
#define LL 1024
#define DM 512
#define DI 1024
#define DS 16
#define DTR 32
#define MM (BB*LL)        // 4096 rows

#define ACT_NONE 0
#define ACT_RELU 1
#define ACT_SP   2

// ---------------- LayerNorm: one block per row of 512 ----------------
__global__ __launch_bounds__(256) void ln_kernel(const float* __restrict__ in,
                                                 float* __restrict__ out) {
  int row = blockIdx.x;
  const float* p = in + (size_t)row * DM;
  float2 v = ((const float2*)p)[threadIdx.x];
  float s  = v.x + v.y;
  float ss = v.x*v.x + v.y*v.y;
  for (int o = 32; o; o >>= 1) { s += __shfl_down(s, o); ss += __shfl_down(ss, o); }
  __shared__ float red[8];
  int wid = threadIdx.x >> 6, lane = threadIdx.x & 63;
  if (lane == 0) { red[wid] = s; red[4+wid] = ss; }
  __syncthreads();
  s  = red[0]+red[1]+red[2]+red[3];
  ss = red[4]+red[5]+red[6]+red[7];
  float mu = s * (1.f/DM);
  float var = ss * (1.f/DM) - mu*mu;
  float rstd = rsqrtf(var + 1e-5f);
  float2 o2; o2.x = (v.x-mu)*rstd; o2.y = (v.y-mu)*rstd;
  ((float2*)(out + (size_t)row*DM))[threadIdx.x] = o2;
}

// ---------------- Generic fp32 NT GEMM: C = act(scale*A@B^T + bias) + res ----
template<int BM, int BN, int BK, int TM, int TN, int ACT>
__global__ __launch_bounds__(256) void gemm_nt(
    const float* __restrict__ A, int lda,
    const float* __restrict__ B, int ldb,
    const float* __restrict__ bias,
    const float* __restrict__ res, int ldres,
    float* __restrict__ C, int ldc,
    int K, float scale)
{
  __shared__ float As[BK][BM + 4];
  __shared__ float Bs[BK][BN + 4];
  const int tid = threadIdx.x;
  const int bm = blockIdx.y * BM;
  const int bn = blockIdx.x * BN;
  const int tx = tid % (BN / TN);
  const int ty = tid / (BN / TN);
  float acc[TM][TN];
  #pragma unroll
  for (int i = 0; i < TM; ++i)
    #pragma unroll
    for (int j = 0; j < TN; ++j) acc[i][j] = 0.f;

  for (int k0 = 0; k0 < K; k0 += BK) {
    for (int i = tid; i < BM*BK/4; i += 256) {
      int r = i / (BK/4);
      int c = (i % (BK/4)) * 4;
      const float4 v = *(const float4*)(A + (size_t)(bm + r)*lda + k0 + c);
      As[c+0][r] = v.x; As[c+1][r] = v.y; As[c+2][r] = v.z; As[c+3][r] = v.w;
    }
    for (int i = tid; i < BN*BK/4; i += 256) {
      int r = i / (BK/4);
      int c = (i % (BK/4)) * 4;
      const float4 v = *(const float4*)(B + (size_t)(bn + r)*ldb + k0 + c);
      Bs[c+0][r] = v.x; Bs[c+1][r] = v.y; Bs[c+2][r] = v.z; Bs[c+3][r] = v.w;
    }
    __syncthreads();
    #pragma unroll
    for (int kk = 0; kk < BK; ++kk) {
      float a[TM], b[TN];
      #pragma unroll
      for (int i = 0; i < TM; i += 4) *(float4*)&a[i] = *(const float4*)&As[kk][ty*TM + i];
      #pragma unroll
      for (int j = 0; j < TN; j += 4) *(float4*)&b[j] = *(const float4*)&Bs[kk][tx*TN + j];
      #pragma unroll
      for (int i = 0; i < TM; ++i)
        #pragma unroll
        for (int j = 0; j < TN; ++j) acc[i][j] = fmaf(a[i], b[j], acc[i][j]);
    }
    __syncthreads();
  }
  #pragma unroll
  for (int i = 0; i < TM; ++i) {
    int m = bm + ty*TM + i;
    #pragma unroll
    for (int j = 0; j < TN; ++j) {
      int nn = bn + tx*TN + j;
      float v = acc[i][j] * scale;
      if (bias) v += bias[nn];
      if (ACT == ACT_RELU) v = fmaxf(v, 0.f);
      if (ACT == ACT_SP)   v = fmaxf(v, 0.f) + log1pf(__expf(-fabsf(v)));
      if (res)  v += res[(size_t)m*ldres + nn];
      C[(size_t)m*ldc + nn] = v;
    }
  }
}

// ---------------- Depthwise causal conv (k=4) + SiLU --------------------
// in: xz (B,L,2*DI), channels 0..DI-1; out: xs (B,L,DI)
__global__ __launch_bounds__(256) void conv_silu_kernel(
    const float* __restrict__ xz, const float* __restrict__ conv_w,
    const float* __restrict__ conv_b, float* __restrict__ xs)
{
  int gid = blockIdx.x * 256 + threadIdx.x;   // B*L*DI = 4M
  int d = gid & (DI-1);
  int l = (gid >> 10) & (LL-1);
  int b = gid >> 20;
  const float* w = conv_w + d*4;
  float s = conv_b[d];
  size_t base = (size_t)b * LL * 2*DI + d;
  #pragma unroll
  for (int k = 0; k < 4; ++k) {
    int ll = l - 3 + k;
    if (ll >= 0) s = fmaf(w[k], xz[base + (size_t)ll * 2*DI], s);
  }
  float sig = 1.f / (1.f + __expf(-s));
  xs[gid] = s * sig;
}

// ---------------- Selective scan (lane-per-state), fused tail ------------
// block = 256 thr = 16 channel-groups x 16 states; handles 16 d's of one b.
// Writes ymul = (y + xs*D) * silu(z) into the xc half of xz (stride 2*DI).
#define SCAN_CH 64
__global__ __launch_bounds__(256) void scan_kernel(
    const float* __restrict__ delta,  // (B,L,DI)
    const float* __restrict__ xs,     // (B,L,DI)
    float* __restrict__ xz,           // (B,L,2*DI): read z, write ymul in xc half
    const float* __restrict__ dbc,    // (B,L,64): Bm at 32+n, Cm at 48+n
    const float* __restrict__ A_log,  // (DI,16)
    const float* __restrict__ D_skip) // (DI)
{
  int blk = blockIdx.x;               // B * DI/16 = 256
  int b   = blk / (DI/16);
  int d0  = (blk % (DI/16)) * 16;
  int tid = threadIdx.x;
  int g = tid >> 4;                   // which channel in the 16-wide group
  int n = tid & 15;                   // state index
  int d = d0 + g;
  float Adn = -__expf(A_log[d*DS + n]);
  float Dd  = D_skip[d];
  __shared__ float s_delta[SCAN_CH][16];
  __shared__ float s_xs[SCAN_CH][16];
  __shared__ float s_z[SCAN_CH][16];
  __shared__ float s_B[SCAN_CH][16];
  __shared__ float s_C[SCAN_CH][16];
  __shared__ float s_y[SCAN_CH][16];
  float h = 0.f;
  for (int l0 = 0; l0 < LL; l0 += SCAN_CH) {
    for (int i = tid; i < SCAN_CH*16; i += 256) {
      int li = i >> 4, dd = i & 15;
      size_t row = (size_t)b*LL + l0 + li;
      s_delta[li][dd] = delta[row*DI + d0 + dd];
      s_xs[li][dd]    = xs[row*DI + d0 + dd];
      s_z[li][dd]     = xz[row*2*DI + DI + d0 + dd];
      s_B[li][dd]     = dbc[row*64 + 32 + dd];
      s_C[li][dd]     = dbc[row*64 + 48 + dd];
    }
    __syncthreads();
    for (int li = 0; li < SCAN_CH; ++li) {
      float dl = s_delta[li][g];
      float xv = s_xs[li][g];
      float dA = __expf(dl * Adn);
      float dBx = dl * xv * s_B[li][n];
      h = fmaf(dA, h, dBx);
      float y = h * s_C[li][n];
      y += __shfl_xor(y, 8, 16);
      y += __shfl_xor(y, 4, 16);
      y += __shfl_xor(y, 2, 16);
      y += __shfl_xor(y, 1, 16);
      if (n == 0) {
        float z = s_z[li][g];
        float sz = z / (1.f + __expf(-z));
        s_y[li][g] = (y + xv*Dd) * sz;
      }
    }
    __syncthreads();
    for (int i = tid; i < SCAN_CH*16; i += 256) {
      int li = i >> 4, dd = i & 15;
      xz[((size_t)b*LL + l0 + li)*2*DI + d0 + dd] = s_y[li][dd];
    }
    __syncthreads();
  }
}

// ---------------- MoE W2 repack: w2cat[n, e*1024+k] = moe_w2[e,n,k] --------
__global__ __launch_bounds__(256) void repack_kernel(
    const float* __restrict__ moe_w2, const float* __restrict__ moe_b2,
    float* __restrict__ w2cat, float* __restrict__ b2avg)
{
  int idx = blockIdx.x * 256 + threadIdx.x;
  if (idx < DM * 2*DI) {
    int nrow = idx >> 11;
    int t = idx & (2*DI - 1);
    int e = t >> 10;
    int k = t & (DI - 1);
    w2cat[idx] = moe_w2[((size_t)e*DM + nrow)*DI + k];
  }
  if (idx < DM) b2avg[idx] = 0.5f * (moe_b2[idx] + moe_b2[DM + idx]);
}

extern "C" void kernel_launch(void* const* d_in, const int* in_sizes, int n_in,
                              void* d_out, int out_size, void* d_ws, size_t ws_size,
                              hipStream_t stream) {
  const float* x         = (const float*)d_in[0];
  const float* in_proj_w = (const float*)d_in[1];
  const float* conv_w    = (const float*)d_in[2];
  const float* conv_b    = (const float*)d_in[3];
  const float* x_proj_w  = (const float*)d_in[4];
  const float* dt_proj_w = (const float*)d_in[5];
  const float* dt_proj_b = (const float*)d_in[6];
  const float* A_log     = (const float*)d_in[7];
  const float* D_skip    = (const float*)d_in[8];
  const float* out_proj_w= (const float*)d_in[9];
  const float* moe_w1    = (const float*)d_in[10];
  const float* moe_b1    = (const float*)d_in[11];
  const float* moe_w2    = (const float*)d_in[12];
  const float* moe_b2    = (const float*)d_in[13];
  float* out = (float*)d_out;

  // Arena (floats). Peak ~93 MB.
  float* ws    = (float*)d_ws;
  float* h1    = ws;                       // 2M  (LN(x))
  float* xzb   = h1 + (size_t)MM*DM;       // 8M  (xz; ymul overlaid in xc half)
  float* xs    = xzb + (size_t)MM*2*DI;    // 4M
  float* delta = xs + (size_t)MM*DI;       // 4M
  float* dbc   = delta + (size_t)MM*DI;    // 256K
  float* w2cat = dbc + (size_t)MM*64;      // 1M
  float* b2avg = w2cat + (size_t)DM*2*DI;  // 512
  float* h2    = b2avg + DM;               // 2M
  float* h2ln  = h2 + (size_t)MM*DM;       // 2M
  float* acat  = xs;                       // reuse xs+delta (8M) after scan

  // 0) repack moe_w2
  repack_kernel<<<(DM*2*DI + 255)/256, 256, 0, stream>>>(moe_w2, moe_b2, w2cat, b2avg);
  // 1) h1 = LN(x)
  ln_kernel<<<MM, 256, 0, stream>>>(x, h1);
  // 2) xz = h1 @ in_proj_w^T   (4096 x 2048, K=512)
  gemm_nt<128,128,16,8,8,ACT_NONE><<<dim3(2*DI/128, MM/128), 256, 0, stream>>>(
      h1, DM, in_proj_w, DM, nullptr, nullptr, 0, xzb, 2*DI, DM, 1.f);
  // 3) xs = silu(causal depthwise conv(xc) + b)
  conv_silu_kernel<<<(MM*DI)/256, 256, 0, stream>>>(xzb, conv_w, conv_b, xs);
  // 4) dbc = xs @ x_proj_w^T   (4096 x 64, K=1024)
  gemm_nt<64,64,16,4,4,ACT_NONE><<<dim3(1, MM/64), 256, 0, stream>>>(
      xs, DI, x_proj_w, DI, nullptr, nullptr, 0, dbc, 64, DI, 1.f);
  // 5) delta = softplus(dt @ dt_proj_w^T + b)   (4096 x 1024, K=32)
  gemm_nt<128,128,16,8,8,ACT_SP><<<dim3(DI/128, MM/128), 256, 0, stream>>>(
      dbc, 64, dt_proj_w, DTR, dt_proj_b, nullptr, 0, delta, DI, DTR, 1.f);
  // 6) selective scan -> ymul (into xc half of xz)
  scan_kernel<<<BB*(DI/16), 256, 0, stream>>>(delta, xs, xzb, dbc, A_log, D_skip);
  // 7) h2 = ymul @ out_proj_w^T + h1   (4096 x 512, K=1024)
  gemm_nt<128,128,16,8,8,ACT_NONE><<<dim3(DM/128, MM/128), 256, 0, stream>>>(
      xzb, 2*DI, out_proj_w, DI, nullptr, h1, DM, h2, DM, DI, 1.f);
  // 8) h2ln = LN(h2)
  ln_kernel<<<MM, 256, 0, stream>>>(h2, h2ln);
  // 9) acat = relu(h2ln @ moe_w1cat^T + b1)   (4096 x 2048, K=512)
  gemm_nt<128,128,16,8,8,ACT_RELU><<<dim3(2*DI/128, MM/128), 256, 0, stream>>>(
      h2ln, DM, moe_w1, DM, moe_b1, nullptr, 0, acat, 2*DI, DM, 1.f);
  // 10) out = 0.5*(acat @ w2cat^T) + b2avg + x   (4096 x 512, K=2048)
  gemm_nt<128,128,16,8,8,ACT_NONE><<<dim3(DM/128, MM/128), 256, 0, stream>>>(
      acat, 2*DI, w2cat, 2*DI, b2avg, x, DM, out, DM, 2*DI, 0.5f);
}

// Round 2
// 488.960 us; speedup vs baseline: 2.3843x; 2.3843x over previous
//
#include <hip/hip_runtime.h>
#include <hip/hip_bf16.h>

// Sizes (match reference)
#define BB 4
#define LL 1024
#define DM 512
#define DI 1024
#define DS 16
#define DTR 32
#define MM (BB*LL)        // 4096 rows

#define ACT_NONE 0
#define ACT_RELU 1
#define ACT_SP   2

typedef __attribute__((ext_vector_type(8))) __bf16 bf16x8;
typedef __attribute__((ext_vector_type(8))) unsigned short us8;
typedef __attribute__((ext_vector_type(4))) float f32x4;

__device__ __forceinline__ unsigned short f2bf(float f) {
  union { float f; unsigned int u; } a; a.f = f;
  unsigned int r = a.u + 0x7fffu + ((a.u >> 16) & 1u);
  return (unsigned short)(r >> 16);
}

__device__ __forceinline__ bf16x8 ld_frag(const unsigned short* p) {
  us8 s = *(const us8*)p;
  return __builtin_bit_cast(bf16x8, s);
}

// ---------------- f32 -> bf16 copy (vectorized x4) ----------------
__global__ __launch_bounds__(256) void f2b4_kernel(const float* __restrict__ in,
                                                   unsigned short* __restrict__ out, int n4) {
  int i = blockIdx.x * 256 + threadIdx.x;
  if (i < n4) {
    float4 v = ((const float4*)in)[i];
    ushort4 o;
    o.x = f2bf(v.x); o.y = f2bf(v.y); o.z = f2bf(v.z); o.w = f2bf(v.w);
    ((ushort4*)out)[i] = o;
  }
}

// ---------------- MoE W2 repack to bf16: w2catb[n, e*1024+k] = bf16(moe_w2[e,n,k])
__global__ __launch_bounds__(256) void repack_kernel(
    const float* __restrict__ moe_w2, const float* __restrict__ moe_b2,
    unsigned short* __restrict__ w2catb, float* __restrict__ b2avg)
{
  int idx = blockIdx.x * 256 + threadIdx.x;
  if (idx < DM * 2*DI) {
    int nrow = idx >> 11;
    int t = idx & (2*DI - 1);
    int e = t >> 10;
    int k = t & (DI - 1);
    w2catb[idx] = f2bf(moe_w2[((size_t)e*DM + nrow)*DI + k]);
  }
  if (idx < DM) b2avg[idx] = 0.5f * (moe_b2[idx] + moe_b2[DM + idx]);
}

// ---------------- LayerNorm: one block per row of 512; fp32 and/or bf16 out --
__global__ __launch_bounds__(256) void ln_kernel(const float* __restrict__ in,
                                                 float* __restrict__ outf,
                                                 unsigned short* __restrict__ outb) {
  int row = blockIdx.x;
  const float* p = in + (size_t)row * DM;
  float2 v = ((const float2*)p)[threadIdx.x];
  float s  = v.x + v.y;
  float ss = v.x*v.x + v.y*v.y;
  for (int o = 32; o; o >>= 1) { s += __shfl_down(s, o); ss += __shfl_down(ss, o); }
  __shared__ float red[8];
  int wid = threadIdx.x >> 6, lane = threadIdx.x & 63;
  if (lane == 0) { red[wid] = s; red[4+wid] = ss; }
  __syncthreads();
  s  = red[0]+red[1]+red[2]+red[3];
  ss = red[4]+red[5]+red[6]+red[7];
  float mu = s * (1.f/DM);
  float var = ss * (1.f/DM) - mu*mu;
  float rstd = rsqrtf(var + 1e-5f);
  float2 o2; o2.x = (v.x-mu)*rstd; o2.y = (v.y-mu)*rstd;
  if (outf) ((float2*)(outf + (size_t)row*DM))[threadIdx.x] = o2;
  if (outb) {
    ushort2 u; u.x = f2bf(o2.x); u.y = f2bf(o2.y);
    ((ushort2*)(outb + (size_t)row*DM))[threadIdx.x] = u;
  }
}

// ---------------- bf16 MFMA GEMM: C = act(scale*A@B^T + bias) + res ---------
// A: (M,K) bf16 row-major lda; B: (N,K) bf16 row-major ldb. 256 thr, 4 waves.
// Wave grid WR x WC, each wave FM x FN fragments of 16x16 (mfma 16x16x32).
template<int BM, int BN, int WR, int WC, int FM, int FN, int ACT, bool OUTF, bool OUTB>
__global__ __launch_bounds__(256) void gemm_mfma(
    const unsigned short* __restrict__ A, int lda,
    const unsigned short* __restrict__ B, int ldb,
    const float* __restrict__ bias,
    const float* __restrict__ res, int ldres,
    float* __restrict__ Cf, unsigned short* __restrict__ Cb, int ldc,
    int K, float scale)
{
  static_assert(WR*WC == 4 && WR*FM*16 == BM && WC*FN*16 == BN, "geom");
  constexpr int BK = 32;
  __shared__ unsigned short As[BM*BK];
  __shared__ unsigned short Bs[BN*BK];
  const int tid = threadIdx.x;
  const int bm = blockIdx.y * BM;
  const int bn = blockIdx.x * BN;
  const int w = tid >> 6, lane = tid & 63;
  const int wr = w / WC, wc = w % WC;
  const int rl = lane & 15, kg = lane >> 4;

  constexpr int AI = BM/64, BI = BN/64;
  us8 ar[AI], br[BI];

  f32x4 acc[FM][FN];
  #pragma unroll
  for (int m = 0; m < FM; ++m)
    #pragma unroll
    for (int n = 0; n < FN; ++n) { f32x4 z = {0.f,0.f,0.f,0.f}; acc[m][n] = z; }

  // prologue: load tile 0 to regs
  #pragma unroll
  for (int it = 0; it < AI; ++it) {
    int e = (it*256 + tid) * 8;
    ar[it] = *(const us8*)(A + (size_t)(bm + (e>>5))*lda + (e&31));
  }
  #pragma unroll
  for (int it = 0; it < BI; ++it) {
    int e = (it*256 + tid) * 8;
    br[it] = *(const us8*)(B + (size_t)(bn + (e>>5))*ldb + (e&31));
  }

  for (int k0 = 0; k0 < K; k0 += BK) {
    #pragma unroll
    for (int it = 0; it < AI; ++it) *(us8*)&As[(it*256 + tid)*8] = ar[it];
    #pragma unroll
    for (int it = 0; it < BI; ++it) *(us8*)&Bs[(it*256 + tid)*8] = br[it];
    __syncthreads();
    if (k0 + BK < K) {  // prefetch next tile into regs (overlaps with MFMA)
      #pragma unroll
      for (int it = 0; it < AI; ++it) {
        int e = (it*256 + tid) * 8;
        ar[it] = *(const us8*)(A + (size_t)(bm + (e>>5))*lda + k0 + BK + (e&31));
      }
      #pragma unroll
      for (int it = 0; it < BI; ++it) {
        int e = (it*256 + tid) * 8;
        br[it] = *(const us8*)(B + (size_t)(bn + (e>>5))*ldb + k0 + BK + (e&31));
      }
    }
    bf16x8 af[FM], bfv[FN];
    #pragma unroll
    for (int m = 0; m < FM; ++m)
      af[m] = ld_frag(&As[(wr*FM*16 + m*16 + rl)*BK + kg*8]);
    #pragma unroll
    for (int n = 0; n < FN; ++n)
      bfv[n] = ld_frag(&Bs[(wc*FN*16 + n*16 + rl)*BK + kg*8]);
    #pragma unroll
    for (int m = 0; m < FM; ++m)
      #pragma unroll
      for (int n = 0; n < FN; ++n)
        acc[m][n] = __builtin_amdgcn_mfma_f32_16x16x32_bf16(af[m], bfv[n], acc[m][n], 0, 0, 0);
    __syncthreads();
  }

  // epilogue: C/D mapping col=lane&15, row=(lane>>4)*4+reg
  #pragma unroll
  for (int m = 0; m < FM; ++m) {
    int row = bm + wr*FM*16 + m*16 + kg*4;
    #pragma unroll
    for (int n = 0; n < FN; ++n) {
      int col = bn + wc*FN*16 + n*16 + rl;
      float bv = bias ? bias[col] : 0.f;
      #pragma unroll
      for (int j = 0; j < 4; ++j) {
        float v = acc[m][n][j] * scale + bv;
        if (ACT == ACT_RELU) v = fmaxf(v, 0.f);
        if (ACT == ACT_SP)   v = fmaxf(v, 0.f) + log1pf(__expf(-fabsf(v)));
        if (res) v += res[(size_t)(row + j)*ldres + col];
        size_t off = (size_t)(row + j)*ldc + col;
        if (OUTF) Cf[off] = v;
        if (OUTB) Cb[off] = f2bf(v);
      }
    }
  }
}

// ---------------- Depthwise causal conv (k=4) + SiLU; fp32 + bf16 out -------
__global__ __launch_bounds__(256) void conv_silu_kernel(
    const float* __restrict__ xz, const float* __restrict__ conv_w,
    const float* __restrict__ conv_b, float* __restrict__ xs,
    unsigned short* __restrict__ xsb)
{
  int gid = blockIdx.x * 256 + threadIdx.x;   // B*L*DI = 4M
  int d = gid & (DI-1);
  int l = (gid >> 10) & (LL-1);
  int b = gid >> 20;
  const float* w = conv_w + d*4;
  float s = conv_b[d];
  size_t base = (size_t)b * LL * 2*DI + d;
  #pragma unroll
  for (int k = 0; k < 4; ++k) {
    int ll = l - 3 + k;
    if (ll >= 0) s = fmaf(w[k], xz[base + (size_t)ll * 2*DI], s);
  }
  float sig = 1.f / (1.f + __expf(-s));
  float v = s * sig;
  xs[gid] = v;
  xsb[gid] = f2bf(v);
}

// ---------------- Selective scan (lane-per-state), fused tail ------------
// Writes ymulb = bf16((y + xs*D) * silu(z)).
#define SCAN_CH 64
__global__ __launch_bounds__(256) void scan_kernel(
    const float* __restrict__ delta,  // (B,L,DI)
    const float* __restrict__ xs,     // (B,L,DI)
    const float* __restrict__ xz,     // (B,L,2*DI): read z
    const float* __restrict__ dbc,    // (B,L,64): Bm at 32+n, Cm at 48+n
    const float* __restrict__ A_log,  // (DI,16)
    const float* __restrict__ D_skip, // (DI)
    unsigned short* __restrict__ ymulb) // (B,L,DI) bf16 out
{
  int blk = blockIdx.x;               // B * DI/16 = 256
  int b   = blk / (DI/16);
  int d0  = (blk % (DI/16)) * 16;
  int tid = threadIdx.x;
  int g = tid >> 4;                   // channel in the 16-wide group
  int n = tid & 15;                   // state index
  int d = d0 + g;
  float Adn = -__expf(A_log[d*DS + n]);
  float Dd  = D_skip[d];
  __shared__ float s_delta[SCAN_CH][16];
  __shared__ float s_xs[SCAN_CH][16];
  __shared__ float s_z[SCAN_CH][16];
  __shared__ float s_B[SCAN_CH][16];
  __shared__ float s_C[SCAN_CH][16];
  __shared__ float s_y[SCAN_CH][16];
  float h = 0.f;
  for (int l0 = 0; l0 < LL; l0 += SCAN_CH) {
    for (int i = tid; i < SCAN_CH*16; i += 256) {
      int li = i >> 4, dd = i & 15;
      size_t row = (size_t)b*LL + l0 + li;
      s_delta[li][dd] = delta[row*DI + d0 + dd];
      s_xs[li][dd]    = xs[row*DI + d0 + dd];
      s_z[li][dd]     = xz[row*2*DI + DI + d0 + dd];
      s_B[li][dd]     = dbc[row*64 + 32 + dd];
      s_C[li][dd]     = dbc[row*64 + 48 + dd];
    }
    __syncthreads();
    for (int li = 0; li < SCAN_CH; ++li) {
      float dl = s_delta[li][g];
      float xv = s_xs[li][g];
      float dA = __expf(dl * Adn);
      float dBx = dl * xv * s_B[li][n];
      h = fmaf(dA, h, dBx);
      float y = h * s_C[li][n];
      y += __shfl_xor(y, 8, 16);
      y += __shfl_xor(y, 4, 16);
      y += __shfl_xor(y, 2, 16);
      y += __shfl_xor(y, 1, 16);
      if (n == 0) {
        float z = s_z[li][g];
        float sz = z / (1.f + __expf(-z));
        s_y[li][g] = (y + xv*Dd) * sz;
      }
    }
    __syncthreads();
    for (int i = tid; i < SCAN_CH*16; i += 256) {
      int li = i >> 4, dd = i & 15;
      ymulb[((size_t)b*LL + l0 + li)*DI + d0 + dd] = f2bf(s_y[li][dd]);
    }
    __syncthreads();
  }
}

extern "C" void kernel_launch(void* const* d_in, const int* in_sizes, int n_in,
                              void* d_out, int out_size, void* d_ws, size_t ws_size,
                              hipStream_t stream) {
  const float* x         = (const float*)d_in[0];
  const float* in_proj_w = (const float*)d_in[1];
  const float* conv_w    = (const float*)d_in[2];
  const float* conv_b    = (const float*)d_in[3];
  const float* x_proj_w  = (const float*)d_in[4];
  const float* dt_proj_w = (const float*)d_in[5];
  const float* dt_proj_b = (const float*)d_in[6];
  const float* A_log     = (const float*)d_in[7];
  const float* D_skip    = (const float*)d_in[8];
  const float* out_proj_w= (const float*)d_in[9];
  const float* moe_w1    = (const float*)d_in[10];
  const float* moe_b1    = (const float*)d_in[11];
  const float* moe_w2    = (const float*)d_in[12];
  const float* moe_b2    = (const float*)d_in[13];
  float* out = (float*)d_out;

  // Arena in floats; total ~23.2M floats = 93 MB (same footprint as round 1).
  float* ws = (float*)d_ws;
  float*          h1    = ws;                                  // 2M f
  unsigned short* h1b   = (unsigned short*)(h1 + 2097152);     // 1M f
  float*          xz    = (float*)((float*)h1b + 1048576);     // 8M f
  float*          xs    = xz + 8388608;                        // 4M f
  unsigned short* xsb   = (unsigned short*)(xs + 4194304);     // 2M f
  float*          delta = (float*)((float*)xsb + 2097152);     // 4M f
  float*          dbc   = delta + 4194304;                     // 256K f
  unsigned short* dbcb  = (unsigned short*)(dbc + 262144);     // 128K f
  float*          wb    = (float*)dbcb + 131072;
  unsigned short* inpb  = (unsigned short*)wb;                 // 512K f (1M elts)
  unsigned short* xpjb  = (unsigned short*)(wb + 524288);      // 32K f (64K elts)
  unsigned short* dtpb  = (unsigned short*)(wb + 524288+32768);        // 16K f
  unsigned short* outpb = (unsigned short*)(wb + 524288+32768+16384);  // 256K f
  unsigned short* w1b   = (unsigned short*)(wb + 524288+32768+16384+262144);        // 512K f
  unsigned short* w2cb  = (unsigned short*)(wb + 524288+32768+16384+262144+524288); // 512K f
  float*          b2avg = wb + 524288+32768+16384+262144+524288+524288;             // 512 f
  // After scan, xz/xs/delta are dead: overlay MoE buffers there.
  unsigned short* ymulb = xsb;                                  // 4M elts (2M f) — overlays xsb (dead after x_proj)
  float*          h2    = xs;                                   // 2M f (xs dead after scan)
  unsigned short* h2lnb = (unsigned short*)(xz + 4194304);      // 2M elts in xz region
  unsigned short* acatb = (unsigned short*)xz;                  // 8M elts (4M f) in xz region

  // 0) weight conversions (bf16) + w2 repack
  f2b4_kernel<<<(1048576/4 + 255)/256, 256, 0, stream>>>(in_proj_w, inpb, 1048576/4);
  f2b4_kernel<<<(65536/4   + 255)/256, 256, 0, stream>>>(x_proj_w,  xpjb, 65536/4);
  f2b4_kernel<<<(32768/4   + 255)/256, 256, 0, stream>>>(dt_proj_w, dtpb, 32768/4);
  f2b4_kernel<<<(524288/4  + 255)/256, 256, 0, stream>>>(out_proj_w,outpb,524288/4);
  f2b4_kernel<<<(1048576/4 + 255)/256, 256, 0, stream>>>(moe_w1,    w1b,  1048576/4);
  repack_kernel<<<(DM*2*DI + 255)/256, 256, 0, stream>>>(moe_w2, moe_b2, w2cb, b2avg);
  // 1) h1 = LN(x)  (fp32 + bf16)
  ln_kernel<<<MM, 256, 0, stream>>>(x, h1, h1b);
  // 2) xz = h1 @ in_proj_w^T   (4096 x 2048, K=512)
  gemm_mfma<128,128,2,2,4,4,ACT_NONE,true,false><<<dim3(16,32), 256, 0, stream>>>(
      h1b, DM, inpb, DM, nullptr, nullptr, 0, xz, nullptr, 2*DI, DM, 1.f);
  // 3) xs = silu(causal depthwise conv(xc) + b)  (fp32 + bf16)
  conv_silu_kernel<<<(MM*DI)/256, 256, 0, stream>>>(xz, conv_w, conv_b, xs, xsb);
  // 4) dbc = xs @ x_proj_w^T   (4096 x 64, K=1024)  (fp32 + bf16)
  gemm_mfma<128,64,4,1,2,4,ACT_NONE,true,true><<<dim3(1,32), 256, 0, stream>>>(
      xsb, DI, xpjb, DI, nullptr, nullptr, 0, dbc, dbcb, 64, DI, 1.f);
  // 5) delta = softplus(dt @ dt_proj_w^T + b)   (4096 x 1024, K=32)
  gemm_mfma<128,128,2,2,4,4,ACT_SP,true,false><<<dim3(8,32), 256, 0, stream>>>(
      dbcb, 64, dtpb, DTR, dt_proj_b, nullptr, 0, delta, nullptr, DI, DTR, 1.f);
  // 6) selective scan -> ymulb (bf16)
  scan_kernel<<<BB*(DI/16), 256, 0, stream>>>(delta, xs, xz, dbc, A_log, D_skip, ymulb);
  // 7) h2 = ymul @ out_proj_w^T + h1   (4096 x 512, K=1024)
  gemm_mfma<128,128,2,2,4,4,ACT_NONE,true,false><<<dim3(4,32), 256, 0, stream>>>(
      ymulb, DI, outpb, DI, nullptr, h1, DM, h2, nullptr, DM, DI, 1.f);
  // 8) h2lnb = LN(h2) (bf16 only)
  ln_kernel<<<MM, 256, 0, stream>>>(h2, nullptr, h2lnb);
  // 9) acatb = relu(h2ln @ moe_w1cat^T + b1)   (4096 x 2048, K=512) bf16 out
  gemm_mfma<128,128,2,2,4,4,ACT_RELU,false,true><<<dim3(16,32), 256, 0, stream>>>(
      h2lnb, DM, w1b, DM, moe_b1, nullptr, 0, nullptr, acatb, 2*DI, DM, 1.f);
  // 10) out = 0.5*(acat @ w2cat^T) + b2avg + x   (4096 x 512, K=2048)
  gemm_mfma<128,128,2,2,4,4,ACT_NONE,true,false><<<dim3(4,32), 256, 0, stream>>>(
      acatb, 2*DI, w2cb, 2*DI, b2avg, x, DM, out, nullptr, DM, 2*DI, 0.5f);
}

// Round 3
// 308.534 us; speedup vs baseline: 3.7786x; 1.5848x over previous
//
#include <hip/hip_runtime.h>
#include <hip/hip_bf16.h>

// Sizes (match reference)
#define BB 4
#define LL 1024
#define DM 512
#define DI 1024
#define DS 16
#define DTR 32
#define MM (BB*LL)        // 4096 rows

#define ACT_NONE 0
#define ACT_RELU 1
#define ACT_SP   2

#define CHUNK 128
#define NCH (LL/CHUNK)    // 8 chunks
#define NSTATE 65536      // B * DI * DS

typedef __attribute__((ext_vector_type(8))) __bf16 bf16x8;
typedef __attribute__((ext_vector_type(8))) unsigned short us8;
typedef __attribute__((ext_vector_type(4))) float f32x4;

__device__ __forceinline__ unsigned short f2bf(float f) {
  union { float f; unsigned int u; } a; a.f = f;
  unsigned int r = a.u + 0x7fffu + ((a.u >> 16) & 1u);
  return (unsigned short)(r >> 16);
}

__device__ __forceinline__ bf16x8 ld_frag(const unsigned short* p) {
  us8 s = *(const us8*)p;
  return __builtin_bit_cast(bf16x8, s);
}

// ---------------- f32 -> bf16 copy (vectorized x4) ----------------
__global__ __launch_bounds__(256) void f2b4_kernel(const float* __restrict__ in,
                                                   unsigned short* __restrict__ out, int n4) {
  int i = blockIdx.x * 256 + threadIdx.x;
  if (i < n4) {
    float4 v = ((const float4*)in)[i];
    ushort4 o;
    o.x = f2bf(v.x); o.y = f2bf(v.y); o.z = f2bf(v.z); o.w = f2bf(v.w);
    ((ushort4*)out)[i] = o;
  }
}

// ---------------- MoE W2 repack to bf16: w2catb[n, e*1024+k] = bf16(moe_w2[e,n,k])
__global__ __launch_bounds__(256) void repack_kernel(
    const float* __restrict__ moe_w2, const float* __restrict__ moe_b2,
    unsigned short* __restrict__ w2catb, float* __restrict__ b2avg)
{
  int idx = blockIdx.x * 256 + threadIdx.x;
  if (idx < DM * 2*DI) {
    int nrow = idx >> 11;
    int t = idx & (2*DI - 1);
    int e = t >> 10;
    int k = t & (DI - 1);
    w2catb[idx] = f2bf(moe_w2[((size_t)e*DM + nrow)*DI + k]);
  }
  if (idx < DM) b2avg[idx] = 0.5f * (moe_b2[idx] + moe_b2[DM + idx]);
}

// ---------------- LayerNorm: one block per row of 512; fp32 and/or bf16 out --
__global__ __launch_bounds__(256) void ln_kernel(const float* __restrict__ in,
                                                 float* __restrict__ outf,
                                                 unsigned short* __restrict__ outb) {
  int row = blockIdx.x;
  const float* p = in + (size_t)row * DM;
  float2 v = ((const float2*)p)[threadIdx.x];
  float s  = v.x + v.y;
  float ss = v.x*v.x + v.y*v.y;
  for (int o = 32; o; o >>= 1) { s += __shfl_down(s, o); ss += __shfl_down(ss, o); }
  __shared__ float red[8];
  int wid = threadIdx.x >> 6, lane = threadIdx.x & 63;
  if (lane == 0) { red[wid] = s; red[4+wid] = ss; }
  __syncthreads();
  s  = red[0]+red[1]+red[2]+red[3];
  ss = red[4]+red[5]+red[6]+red[7];
  float mu = s * (1.f/DM);
  float var = ss * (1.f/DM) - mu*mu;
  float rstd = rsqrtf(var + 1e-5f);
  float2 o2; o2.x = (v.x-mu)*rstd; o2.y = (v.y-mu)*rstd;
  if (outf) ((float2*)(outf + (size_t)row*DM))[threadIdx.x] = o2;
  if (outb) {
    ushort2 u; u.x = f2bf(o2.x); u.y = f2bf(o2.y);
    ((ushort2*)(outb + (size_t)row*DM))[threadIdx.x] = u;
  }
}

// ---------------- bf16 MFMA GEMM: C = act(scale*A@B^T + bias) + res ---------
template<int BM, int BN, int WR, int WC, int FM, int FN, int ACT, bool OUTF, bool OUTB>
__global__ __launch_bounds__(256) void gemm_mfma(
    const unsigned short* __restrict__ A, int lda,
    const unsigned short* __restrict__ B, int ldb,
    const float* __restrict__ bias,
    const float* __restrict__ res, int ldres,
    float* __restrict__ Cf, unsigned short* __restrict__ Cb, int ldc,
    int K, float scale)
{
  static_assert(WR*WC == 4 && WR*FM*16 == BM && WC*FN*16 == BN, "geom");
  constexpr int BK = 32;
  __shared__ unsigned short As[BM*BK];
  __shared__ unsigned short Bs[BN*BK];
  const int tid = threadIdx.x;
  const int bm = blockIdx.y * BM;
  const int bn = blockIdx.x * BN;
  const int w = tid >> 6, lane = tid & 63;
  const int wr = w / WC, wc = w % WC;
  const int rl = lane & 15, kg = lane >> 4;

  constexpr int AI = BM/64, BI = BN/64;
  us8 ar[AI], br[BI];

  f32x4 acc[FM][FN];
  #pragma unroll
  for (int m = 0; m < FM; ++m)
    #pragma unroll
    for (int n = 0; n < FN; ++n) { f32x4 z = {0.f,0.f,0.f,0.f}; acc[m][n] = z; }

  #pragma unroll
  for (int it = 0; it < AI; ++it) {
    int e = (it*256 + tid) * 8;
    ar[it] = *(const us8*)(A + (size_t)(bm + (e>>5))*lda + (e&31));
  }
  #pragma unroll
  for (int it = 0; it < BI; ++it) {
    int e = (it*256 + tid) * 8;
    br[it] = *(const us8*)(B + (size_t)(bn + (e>>5))*ldb + (e&31));
  }

  for (int k0 = 0; k0 < K; k0 += BK) {
    #pragma unroll
    for (int it = 0; it < AI; ++it) *(us8*)&As[(it*256 + tid)*8] = ar[it];
    #pragma unroll
    for (int it = 0; it < BI; ++it) *(us8*)&Bs[(it*256 + tid)*8] = br[it];
    __syncthreads();
    if (k0 + BK < K) {
      #pragma unroll
      for (int it = 0; it < AI; ++it) {
        int e = (it*256 + tid) * 8;
        ar[it] = *(const us8*)(A + (size_t)(bm + (e>>5))*lda + k0 + BK + (e&31));
      }
      #pragma unroll
      for (int it = 0; it < BI; ++it) {
        int e = (it*256 + tid) * 8;
        br[it] = *(const us8*)(B + (size_t)(bn + (e>>5))*ldb + k0 + BK + (e&31));
      }
    }
    bf16x8 af[FM], bfv[FN];
    #pragma unroll
    for (int m = 0; m < FM; ++m)
      af[m] = ld_frag(&As[(wr*FM*16 + m*16 + rl)*BK + kg*8]);
    #pragma unroll
    for (int n = 0; n < FN; ++n)
      bfv[n] = ld_frag(&Bs[(wc*FN*16 + n*16 + rl)*BK + kg*8]);
    #pragma unroll
    for (int m = 0; m < FM; ++m)
      #pragma unroll
      for (int n = 0; n < FN; ++n)
        acc[m][n] = __builtin_amdgcn_mfma_f32_16x16x32_bf16(af[m], bfv[n], acc[m][n], 0, 0, 0);
    __syncthreads();
  }

  #pragma unroll
  for (int m = 0; m < FM; ++m) {
    int row = bm + wr*FM*16 + m*16 + kg*4;
    #pragma unroll
    for (int n = 0; n < FN; ++n) {
      int col = bn + wc*FN*16 + n*16 + rl;
      float bv = bias ? bias[col] : 0.f;
      #pragma unroll
      for (int j = 0; j < 4; ++j) {
        float v = acc[m][n][j] * scale + bv;
        if (ACT == ACT_RELU) v = fmaxf(v, 0.f);
        if (ACT == ACT_SP)   v = fmaxf(v, 0.f) + log1pf(__expf(-fabsf(v)));
        if (res) v += res[(size_t)(row + j)*ldres + col];
        size_t off = (size_t)(row + j)*ldc + col;
        if (OUTF) Cf[off] = v;
        if (OUTB) Cb[off] = f2bf(v);
      }
    }
  }
}

// ---------------- Depthwise causal conv (k=4) + SiLU; fp32 + bf16 out -------
__global__ __launch_bounds__(256) void conv_silu_kernel(
    const float* __restrict__ xz, const float* __restrict__ conv_w,
    const float* __restrict__ conv_b, float* __restrict__ xs,
    unsigned short* __restrict__ xsb)
{
  int gid = blockIdx.x * 256 + threadIdx.x;   // B*L*DI = 4M
  int d = gid & (DI-1);
  int l = (gid >> 10) & (LL-1);
  int b = gid >> 20;
  const float* w = conv_w + d*4;
  float s = conv_b[d];
  size_t base = (size_t)b * LL * 2*DI + d;
  #pragma unroll
  for (int k = 0; k < 4; ++k) {
    int ll = l - 3 + k;
    if (ll >= 0) s = fmaf(w[k], xz[base + (size_t)ll * 2*DI], s);
  }
  float sig = 1.f / (1.f + __expf(-s));
  float v = s * sig;
  xs[gid] = v;
  xsb[gid] = f2bf(v);
}

// ============ Chunked selective scan =========================================
// Recurrence h = dA*h + dBx over L, split into NCH chunks of CHUNK.
// Phase 1: per (b,d,n,chunk) run from h=0, emit P=exp(A*sum(delta)), Q=h_end.
// Stitch : H[c] = P[c-1]*H[c-1] + Q[c-1] (8 steps, coalesced layout t+65536*c).
// Phase 2: re-run chunk from H, reduce y over n, fused D-skip + silu(z) tail.
// Block = 16 d x 16 n; grid = B * 64 dgroups * NCH.

__global__ __launch_bounds__(256) void scan_p1(
    const float* __restrict__ delta,  // (B,L,DI)
    const float* __restrict__ xs,     // (B,L,DI)
    const float* __restrict__ dbc,    // (B,L,64): Bm at 32+n
    const float* __restrict__ A_log,  // (DI,16)
    float* __restrict__ P, float* __restrict__ Q)
{
  int blk = blockIdx.x;
  int c  = blk & (NCH-1);
  int dg = (blk >> 3) & 63;
  int b  = blk >> 9;
  int tid = threadIdx.x;
  int g = tid >> 4, n = tid & 15;
  int d0 = dg*16;
  float Adn2 = -__expf(A_log[(d0+g)*DS + n]) * 1.44269504f;  // A*log2(e)
  __shared__ float s_d[64][16], s_dx[64][16], s_B[64][16];
  float h = 0.f, S = 0.f;
  int lbase = c*CHUNK;
  for (int l0 = 0; l0 < CHUNK; l0 += 64) {
    {
      int li = tid >> 2, dd = (tid & 3) * 4;
      size_t row = (size_t)b*LL + lbase + l0 + li;
      float4 vd = *(const float4*)(delta + row*DI + d0 + dd);
      float4 vx = *(const float4*)(xs    + row*DI + d0 + dd);
      float4 vB = *(const float4*)(dbc   + row*64 + 32 + dd);
      *(float4*)&s_d[li][dd] = vd;
      float4 dx; dx.x=vd.x*vx.x; dx.y=vd.y*vx.y; dx.z=vd.z*vx.z; dx.w=vd.w*vx.w;
      *(float4*)&s_dx[li][dd] = dx;
      *(float4*)&s_B[li][dd] = vB;
    }
    __syncthreads();
    #pragma unroll 8
    for (int li = 0; li < 64; ++li) {
      float dl = s_d[li][g];
      float dA = exp2f(dl * Adn2);
      h = fmaf(dA, h, s_dx[li][g] * s_B[li][n]);
      S += dl;
    }
    __syncthreads();
  }
  int base = ((b*64 + dg)*256 + g*16 + n) + NSTATE*c;
  P[base] = exp2f(S * Adn2);
  Q[base] = h;
}

__global__ __launch_bounds__(256) void scan_stitch(
    const float* __restrict__ P, const float* __restrict__ Q,
    float* __restrict__ H)
{
  int t = blockIdx.x * 256 + threadIdx.x;   // 65536
  float h = 0.f;
  #pragma unroll
  for (int c = 0; c < NCH; ++c) {
    H[t + NSTATE*c] = h;
    h = fmaf(P[t + NSTATE*c], h, Q[t + NSTATE*c]);
  }
}

__global__ __launch_bounds__(256) void scan_p2(
    const float* __restrict__ delta,
    const float* __restrict__ xs,
    const float* __restrict__ xz,     // read z half
    const float* __restrict__ dbc,    // Bm at 32+n, Cm at 48+n
    const float* __restrict__ A_log,
    const float* __restrict__ D_skip,
    const float* __restrict__ H,
    unsigned short* __restrict__ ymulb) // (B,L,DI) bf16 out
{
  int blk = blockIdx.x;
  int c  = blk & (NCH-1);
  int dg = (blk >> 3) & 63;
  int b  = blk >> 9;
  int tid = threadIdx.x;
  int g = tid >> 4, n = tid & 15;
  int d0 = dg*16;
  float Adn2 = -__expf(A_log[(d0+g)*DS + n]) * 1.44269504f;
  __shared__ float s_d[64][16], s_dx[64][16], s_xs[64][16], s_z[64][16];
  __shared__ float s_B[64][16], s_C[64][16], s_y[64][16];
  __shared__ float s_D[16];
  if (tid < 16) s_D[tid] = D_skip[d0 + tid];
  float h = H[((b*64 + dg)*256 + g*16 + n) + NSTATE*c];
  int lbase = c*CHUNK;
  for (int l0 = 0; l0 < CHUNK; l0 += 64) {
    {
      int li = tid >> 2, dd = (tid & 3) * 4;
      size_t row = (size_t)b*LL + lbase + l0 + li;
      float4 vd = *(const float4*)(delta + row*DI + d0 + dd);
      float4 vx = *(const float4*)(xs    + row*DI + d0 + dd);
      float4 vz = *(const float4*)(xz    + row*2*DI + DI + d0 + dd);
      float4 vB = *(const float4*)(dbc   + row*64 + 32 + dd);
      float4 vC = *(const float4*)(dbc   + row*64 + 48 + dd);
      *(float4*)&s_d[li][dd] = vd;
      float4 dx; dx.x=vd.x*vx.x; dx.y=vd.y*vx.y; dx.z=vd.z*vx.z; dx.w=vd.w*vx.w;
      *(float4*)&s_dx[li][dd] = dx;
      *(float4*)&s_xs[li][dd] = vx;
      float4 sz;
      sz.x = vz.x / (1.f + __expf(-vz.x));
      sz.y = vz.y / (1.f + __expf(-vz.y));
      sz.z = vz.z / (1.f + __expf(-vz.z));
      sz.w = vz.w / (1.f + __expf(-vz.w));
      *(float4*)&s_z[li][dd] = sz;
      *(float4*)&s_B[li][dd] = vB;
      *(float4*)&s_C[li][dd] = vC;
    }
    __syncthreads();
    for (int li = 0; li < 64; ++li) {
      float dl = s_d[li][g];
      float dA = exp2f(dl * Adn2);
      h = fmaf(dA, h, s_dx[li][g] * s_B[li][n]);
      float y = h * s_C[li][n];
      y += __shfl_xor(y, 8);
      y += __shfl_xor(y, 4);
      y += __shfl_xor(y, 2);
      y += __shfl_xor(y, 1);
      if (n == 0) s_y[li][g] = y;
    }
    __syncthreads();
    for (int i = tid; i < 64*16; i += 256) {
      int li = i >> 4, dd = i & 15;
      float v = (s_y[li][dd] + s_xs[li][dd]*s_D[dd]) * s_z[li][dd];
      ymulb[((size_t)b*LL + lbase + l0 + li)*DI + d0 + dd] = f2bf(v);
    }
    __syncthreads();
  }
}

extern "C" void kernel_launch(void* const* d_in, const int* in_sizes, int n_in,
                              void* d_out, int out_size, void* d_ws, size_t ws_size,
                              hipStream_t stream) {
  const float* x         = (const float*)d_in[0];
  const float* in_proj_w = (const float*)d_in[1];
  const float* conv_w    = (const float*)d_in[2];
  const float* conv_b    = (const float*)d_in[3];
  const float* x_proj_w  = (const float*)d_in[4];
  const float* dt_proj_w = (const float*)d_in[5];
  const float* dt_proj_b = (const float*)d_in[6];
  const float* A_log     = (const float*)d_in[7];
  const float* D_skip    = (const float*)d_in[8];
  const float* out_proj_w= (const float*)d_in[9];
  const float* moe_w1    = (const float*)d_in[10];
  const float* moe_b1    = (const float*)d_in[11];
  const float* moe_w2    = (const float*)d_in[12];
  const float* moe_b2    = (const float*)d_in[13];
  float* out = (float*)d_out;

  // Arena in floats; total ~23.2M floats = 93 MB.
  float* ws = (float*)d_ws;
  float*          h1    = ws;                                  // 2M f
  unsigned short* h1b   = (unsigned short*)(h1 + 2097152);     // 1M f region
  float*          xz    = (float*)((float*)h1b + 1048576);     // 8M f
  float*          xs    = xz + 8388608;                        // 4M f
  unsigned short* xsb   = (unsigned short*)(xs + 4194304);     // 2M f region
  float*          delta = (float*)((float*)xsb + 2097152);     // 4M f
  float*          dbc   = delta + 4194304;                     // 256K f
  unsigned short* dbcb  = (unsigned short*)(dbc + 262144);     // 128K f region
  float*          wb    = (float*)dbcb + 131072;
  unsigned short* inpb  = (unsigned short*)wb;                 // 512K f (1M elts)
  unsigned short* xpjb  = (unsigned short*)(wb + 524288);      // 32K f
  unsigned short* dtpb  = (unsigned short*)(wb + 524288+32768);        // 16K f
  unsigned short* outpb = (unsigned short*)(wb + 524288+32768+16384);  // 256K f
  unsigned short* w1b   = (unsigned short*)(wb + 524288+32768+16384+262144);        // 512K f
  unsigned short* w2cb  = (unsigned short*)(wb + 524288+32768+16384+262144+524288); // 512K f
  float*          b2avg = wb + 524288+32768+16384+262144+524288+524288;             // 512 f
  // Overlays:
  unsigned short* ymulb = xsb;                                  // scan out (xsb dead after x_proj)
  float*          h2    = xs;                                   // (xs dead after scan)
  unsigned short* h2lnb = (unsigned short*)(xz + 4194304);      // in xz region
  unsigned short* acatb = (unsigned short*)xz;                  // in xz region
  // Scan scratch overlays (dead after in_proj GEMM):
  float*          Pbuf  = (float*)inpb;                         // 512K f  (inpb: 1M bf16)
  float*          Qbuf  = (float*)h1b;                          // 512K f  (h1b: 1M bf16 = 512K f... uses first half)
  float*          Hbuf  = (float*)h1b + 524288;                 // wait: h1b region is 1M floats
  // NOTE: h1b region is 1M floats (declared as 1M f above): Q in [0,512K), H in [512K,1M).

  // 0) weight conversions (bf16) + w2 repack
  f2b4_kernel<<<(1048576/4 + 255)/256, 256, 0, stream>>>(in_proj_w, inpb, 1048576/4);
  f2b4_kernel<<<(65536/4   + 255)/256, 256, 0, stream>>>(x_proj_w,  xpjb, 65536/4);
  f2b4_kernel<<<(32768/4   + 255)/256, 256, 0, stream>>>(dt_proj_w, dtpb, 32768/4);
  f2b4_kernel<<<(524288/4  + 255)/256, 256, 0, stream>>>(out_proj_w,outpb,524288/4);
  f2b4_kernel<<<(1048576/4 + 255)/256, 256, 0, stream>>>(moe_w1,    w1b,  1048576/4);
  repack_kernel<<<(DM*2*DI + 255)/256, 256, 0, stream>>>(moe_w2, moe_b2, w2cb, b2avg);
  // 1) h1 = LN(x)  (fp32 + bf16)
  ln_kernel<<<MM, 256, 0, stream>>>(x, h1, h1b);
  // 2) xz = h1 @ in_proj_w^T   (4096 x 2048, K=512)
  gemm_mfma<128,128,2,2,4,4,ACT_NONE,true,false><<<dim3(16,32), 256, 0, stream>>>(
      h1b, DM, inpb, DM, nullptr, nullptr, 0, xz, nullptr, 2*DI, DM, 1.f);
  // 3) xs = silu(causal depthwise conv(xc) + b)  (fp32 + bf16)
  conv_silu_kernel<<<(MM*DI)/256, 256, 0, stream>>>(xz, conv_w, conv_b, xs, xsb);
  // 4) dbc = xs @ x_proj_w^T   (4096 x 64, K=1024)  (fp32 + bf16)
  gemm_mfma<128,64,4,1,2,4,ACT_NONE,true,true><<<dim3(1,32), 256, 0, stream>>>(
      xsb, DI, xpjb, DI, nullptr, nullptr, 0, dbc, dbcb, 64, DI, 1.f);
  // 5) delta = softplus(dt @ dt_proj_w^T + b)   (4096 x 1024, K=32)
  gemm_mfma<128,128,2,2,4,4,ACT_SP,true,false><<<dim3(8,32), 256, 0, stream>>>(
      dbcb, 64, dtpb, DTR, dt_proj_b, nullptr, 0, delta, nullptr, DI, DTR, 1.f);
  // 6) chunked selective scan -> ymulb (bf16). Scratch P/Q/H overlay inpb/h1b
  //    (both dead after step 2).
  scan_p1<<<BB*64*NCH, 256, 0, stream>>>(delta, xs, dbc, A_log, Pbuf, Qbuf);
  scan_stitch<<<NSTATE/256, 256, 0, stream>>>(Pbuf, Qbuf, Hbuf);
  scan_p2<<<BB*64*NCH, 256, 0, stream>>>(delta, xs, xz, dbc, A_log, D_skip, Hbuf, ymulb);
  // 7) h2 = ymul @ out_proj_w^T + h1   (4096 x 512, K=1024)
  gemm_mfma<128,128,2,2,4,4,ACT_NONE,true,false><<<dim3(4,32), 256, 0, stream>>>(
      ymulb, DI, outpb, DI, nullptr, h1, DM, h2, nullptr, DM, DI, 1.f);
  // 8) h2lnb = LN(h2) (bf16 only)
  ln_kernel<<<MM, 256, 0, stream>>>(h2, nullptr, h2lnb);
  // 9) acatb = relu(h2ln @ moe_w1cat^T + b1)   (4096 x 2048, K=512) bf16 out
  gemm_mfma<128,128,2,2,4,4,ACT_RELU,false,true><<<dim3(16,32), 256, 0, stream>>>(
      h2lnb, DM, w1b, DM, moe_b1, nullptr, 0, nullptr, acatb, 2*DI, DM, 1.f);
  // 10) out = 0.5*(acat @ w2cat^T) + b2avg + x   (4096 x 512, K=2048)
  gemm_mfma<128,128,2,2,4,4,ACT_NONE,true,false><<<dim3(4,32), 256, 0, stream>>>(
      acatb, 2*DI, w2cb, 2*DI, b2avg, x, DM, out, nullptr, DM, 2*DI, 0.5f);
}

// Round 4
// 298.030 us; speedup vs baseline: 3.9118x; 1.0352x over previous
//
#include <hip/hip_runtime.h>
#include <hip/hip_bf16.h>

// Sizes (match reference)
#define BB 4
#define LL 1024
#define DM 512
#define DI 1024
#define DS 16
#define DTR 32
#define MM (BB*LL)        // 4096 rows

#define ACT_NONE 0
#define ACT_RELU 1
#define ACT_SP   2

#define CHUNK 128
#define NCH (LL/CHUNK)    // 8 chunks
#define NSTATE 65536      // B * DI * DS

typedef __attribute__((ext_vector_type(8))) __bf16 bf16x8;
typedef __attribute__((ext_vector_type(8))) unsigned short us8;
typedef __attribute__((ext_vector_type(4))) float f32x4;

__device__ __forceinline__ unsigned short f2bf(float f) {
  union { float f; unsigned int u; } a; a.f = f;
  unsigned int r = a.u + 0x7fffu + ((a.u >> 16) & 1u);
  return (unsigned short)(r >> 16);
}

__device__ __forceinline__ bf16x8 ld_frag(const unsigned short* p) {
  us8 s = *(const us8*)p;
  return __builtin_bit_cast(bf16x8, s);
}

// async global->LDS, 16B per lane. LDS dest must be wave-uniform base + lane*16.
__device__ __forceinline__ void gload16(const void* g, void* l) {
  __builtin_amdgcn_global_load_lds(
      (const __attribute__((address_space(1))) void*)g,
      (__attribute__((address_space(3))) void*)l, 16, 0, 0);
}

// ---------------- f32 -> bf16 copy (vectorized x4) ----------------
__global__ __launch_bounds__(256) void f2b4_kernel(const float* __restrict__ in,
                                                   unsigned short* __restrict__ out, int n4) {
  int i = blockIdx.x * 256 + threadIdx.x;
  if (i < n4) {
    float4 v = ((const float4*)in)[i];
    ushort4 o;
    o.x = f2bf(v.x); o.y = f2bf(v.y); o.z = f2bf(v.z); o.w = f2bf(v.w);
    ((ushort4*)out)[i] = o;
  }
}

// ---------------- MoE W2 repack to bf16 ----------------
__global__ __launch_bounds__(256) void repack_kernel(
    const float* __restrict__ moe_w2, const float* __restrict__ moe_b2,
    unsigned short* __restrict__ w2catb, float* __restrict__ b2avg)
{
  int idx = blockIdx.x * 256 + threadIdx.x;
  if (idx < DM * 2*DI) {
    int nrow = idx >> 11;
    int t = idx & (2*DI - 1);
    int e = t >> 10;
    int k = t & (DI - 1);
    w2catb[idx] = f2bf(moe_w2[((size_t)e*DM + nrow)*DI + k]);
  }
  if (idx < DM) b2avg[idx] = 0.5f * (moe_b2[idx] + moe_b2[DM + idx]);
}

// ---------------- LayerNorm ----------------
__global__ __launch_bounds__(256) void ln_kernel(const float* __restrict__ in,
                                                 float* __restrict__ outf,
                                                 unsigned short* __restrict__ outb) {
  int row = blockIdx.x;
  const float* p = in + (size_t)row * DM;
  float2 v = ((const float2*)p)[threadIdx.x];
  float s  = v.x + v.y;
  float ss = v.x*v.x + v.y*v.y;
  for (int o = 32; o; o >>= 1) { s += __shfl_down(s, o); ss += __shfl_down(ss, o); }
  __shared__ float red[8];
  int wid = threadIdx.x >> 6, lane = threadIdx.x & 63;
  if (lane == 0) { red[wid] = s; red[4+wid] = ss; }
  __syncthreads();
  s  = red[0]+red[1]+red[2]+red[3];
  ss = red[4]+red[5]+red[6]+red[7];
  float mu = s * (1.f/DM);
  float var = ss * (1.f/DM) - mu*mu;
  float rstd = rsqrtf(var + 1e-5f);
  float2 o2; o2.x = (v.x-mu)*rstd; o2.y = (v.y-mu)*rstd;
  if (outf) ((float2*)(outf + (size_t)row*DM))[threadIdx.x] = o2;
  if (outb) {
    ushort2 u; u.x = f2bf(o2.x); u.y = f2bf(o2.y);
    ((ushort2*)(outb + (size_t)row*DM))[threadIdx.x] = u;
  }
}

// ---------------- bf16 MFMA GEMM (global_load_lds staging, m97 structure) ---
template<int BM, int BN, int WR, int WC, int FM, int FN, int ACT, bool OUTF, bool OUTB>
__global__ __launch_bounds__(256) void gemm_mfma(
    const unsigned short* __restrict__ A, int lda,
    const unsigned short* __restrict__ B, int ldb,
    const float* __restrict__ bias,
    const float* __restrict__ res, int ldres,
    float* __restrict__ Cf, unsigned short* __restrict__ Cb, int ldc,
    int K, float scale)
{
  static_assert(WR*WC == 4 && WR*FM*16 == BM && WC*FN*16 == BN, "geom");
  constexpr int BK = 32;
  __shared__ unsigned short As[BM*BK];
  __shared__ unsigned short Bs[BN*BK];
  const int tid = threadIdx.x;
  const int bm = blockIdx.y * BM;
  const int bn = blockIdx.x * BN;
  const int w = tid >> 6, lane = tid & 63;
  const int wr = w / WC, wc = w % WC;
  const int rl = lane & 15, kg = lane >> 4;

  constexpr int AI = BM/64, BI = BN/64;

  f32x4 acc[FM][FN];
  #pragma unroll
  for (int m = 0; m < FM; ++m)
    #pragma unroll
    for (int n = 0; n < FN; ++n) { f32x4 z = {0.f,0.f,0.f,0.f}; acc[m][n] = z; }

  for (int k0 = 0; k0 < K; k0 += BK) {
    #pragma unroll
    for (int it = 0; it < AI; ++it) {
      int e = (it*256 + tid) * 8;
      gload16(A + (size_t)(bm + (e>>5))*lda + k0 + (e&31), &As[e]);
    }
    #pragma unroll
    for (int it = 0; it < BI; ++it) {
      int e = (it*256 + tid) * 8;
      gload16(B + (size_t)(bn + (e>>5))*ldb + k0 + (e&31), &Bs[e]);
    }
    __syncthreads();   // drains vmcnt: LDS tile ready
    bf16x8 af[FM], bfv[FN];
    #pragma unroll
    for (int m = 0; m < FM; ++m)
      af[m] = ld_frag(&As[(wr*FM*16 + m*16 + rl)*BK + kg*8]);
    #pragma unroll
    for (int n = 0; n < FN; ++n)
      bfv[n] = ld_frag(&Bs[(wc*FN*16 + n*16 + rl)*BK + kg*8]);
    #pragma unroll
    for (int m = 0; m < FM; ++m)
      #pragma unroll
      for (int n = 0; n < FN; ++n)
        acc[m][n] = __builtin_amdgcn_mfma_f32_16x16x32_bf16(af[m], bfv[n], acc[m][n], 0, 0, 0);
    __syncthreads();   // all reads done before next tile overwrites
  }

  #pragma unroll
  for (int m = 0; m < FM; ++m) {
    int row = bm + wr*FM*16 + m*16 + kg*4;
    #pragma unroll
    for (int n = 0; n < FN; ++n) {
      int col = bn + wc*FN*16 + n*16 + rl;
      float bv = bias ? bias[col] : 0.f;
      #pragma unroll
      for (int j = 0; j < 4; ++j) {
        float v = acc[m][n][j] * scale + bv;
        if (ACT == ACT_RELU) v = fmaxf(v, 0.f);
        if (ACT == ACT_SP)   v = fmaxf(v, 0.f) + log1pf(__expf(-fabsf(v)));
        if (res) v += res[(size_t)(row + j)*ldres + col];
        size_t off = (size_t)(row + j)*ldc + col;
        if (OUTF) Cf[off] = v;
        if (OUTB) Cb[off] = f2bf(v);
      }
    }
  }
}

// ---------------- Depthwise causal conv (k=4) + SiLU --------------------
__global__ __launch_bounds__(256) void conv_silu_kernel(
    const float* __restrict__ xz, const float* __restrict__ conv_w,
    const float* __restrict__ conv_b, float* __restrict__ xs,
    unsigned short* __restrict__ xsb)
{
  int gid = blockIdx.x * 256 + threadIdx.x;   // B*L*DI = 4M
  int d = gid & (DI-1);
  int l = (gid >> 10) & (LL-1);
  int b = gid >> 20;
  const float* w = conv_w + d*4;
  float s = conv_b[d];
  size_t base = (size_t)b * LL * 2*DI + d;
  #pragma unroll
  for (int k = 0; k < 4; ++k) {
    int ll = l - 3 + k;
    if (ll >= 0) s = fmaf(w[k], xz[base + (size_t)ll * 2*DI], s);
  }
  float sig = 1.f / (1.f + __expf(-s));
  float v = s * sig;
  xs[gid] = v;
  xsb[gid] = f2bf(v);
}

// ============ Chunked selective scan =========================================
// Phase 1: per (b,dgroup,chunk): run from h=0, emit P=exp(A*sum(delta)), Q=h_end.
// Transposed LDS staging: s_*[16][68] so the step loop reads float4 per 4 steps.
__global__ __launch_bounds__(256) void scan_p1(
    const float* __restrict__ delta,
    const float* __restrict__ xs,
    const float* __restrict__ dbc,
    const float* __restrict__ A_log,
    float* __restrict__ P, float* __restrict__ Q)
{
  int blk = blockIdx.x;
  int c  = blk & (NCH-1);
  int dg = (blk >> 3) & 63;
  int b  = blk >> 9;
  int tid = threadIdx.x;
  int g = tid >> 4, n = tid & 15;
  int d0 = dg*16;
  float Adn2 = -__expf(A_log[(d0+g)*DS + n]) * 1.44269504f;
  __shared__ float s_d[16][68], s_dx[16][68], s_B[16][68];
  float h = 0.f, S = 0.f;
  int lbase = c*CHUNK;
  for (int l0 = 0; l0 < CHUNK; l0 += 64) {
    {
      int li = tid >> 2, dd = (tid & 3) * 4;
      size_t row = (size_t)b*LL + lbase + l0 + li;
      float4 vd = *(const float4*)(delta + row*DI + d0 + dd);
      float4 vx = *(const float4*)(xs    + row*DI + d0 + dd);
      float4 vB = *(const float4*)(dbc   + row*64 + 32 + dd);
      s_d [dd+0][li]=vd.x; s_d [dd+1][li]=vd.y; s_d [dd+2][li]=vd.z; s_d [dd+3][li]=vd.w;
      s_dx[dd+0][li]=vd.x*vx.x; s_dx[dd+1][li]=vd.y*vx.y; s_dx[dd+2][li]=vd.z*vx.z; s_dx[dd+3][li]=vd.w*vx.w;
      s_B [dd+0][li]=vB.x; s_B [dd+1][li]=vB.y; s_B [dd+2][li]=vB.z; s_B [dd+3][li]=vB.w;
    }
    __syncthreads();
    #pragma unroll
    for (int q4 = 0; q4 < 64; q4 += 4) {
      float4 vd  = *(const float4*)&s_d[g][q4];
      float4 vdx = *(const float4*)&s_dx[g][q4];
      float4 vB  = *(const float4*)&s_B[n][q4];
      float dA;
      dA = exp2f(vd.x*Adn2); h = fmaf(dA, h, vdx.x*vB.x); S += vd.x;
      dA = exp2f(vd.y*Adn2); h = fmaf(dA, h, vdx.y*vB.y); S += vd.y;
      dA = exp2f(vd.z*Adn2); h = fmaf(dA, h, vdx.z*vB.z); S += vd.z;
      dA = exp2f(vd.w*Adn2); h = fmaf(dA, h, vdx.w*vB.w); S += vd.w;
    }
    __syncthreads();
  }
  int base = ((b*64 + dg)*256 + g*16 + n) + NSTATE*c;
  P[base] = exp2f(S * Adn2);
  Q[base] = h;
}

__global__ __launch_bounds__(256) void scan_stitch(
    const float* __restrict__ P, const float* __restrict__ Q,
    float* __restrict__ H)
{
  int t = blockIdx.x * 256 + threadIdx.x;   // 65536
  float h = 0.f;
  #pragma unroll
  for (int c = 0; c < NCH; ++c) {
    H[t + NSTATE*c] = h;
    h = fmaf(P[t + NSTATE*c], h, Q[t + NSTATE*c]);
  }
}

// Phase 2: re-run chunk from stitched H; deferred reduction via LDS partials
// (no shuffles, no divergence). Every 16 steps: conflict-free n-sum + fused
// tail (y + xs*D)*silu(z) -> bf16 global write.
__global__ __launch_bounds__(256) void scan_p2(
    const float* __restrict__ delta,
    const float* __restrict__ xs,
    const float* __restrict__ xz,     // read z half
    const float* __restrict__ dbc,    // Bm at 32+n, Cm at 48+n
    const float* __restrict__ A_log,
    const float* __restrict__ D_skip,
    const float* __restrict__ H,
    unsigned short* __restrict__ ymulb)
{
  int blk = blockIdx.x;
  int c  = blk & (NCH-1);
  int dg = (blk >> 3) & 63;
  int b  = blk >> 9;
  int tid = threadIdx.x;
  int g = tid >> 4, n = tid & 15;
  int d0 = dg*16;
  float Adn2 = -__expf(A_log[(d0+g)*DS + n]) * 1.44269504f;
  __shared__ float s_d[16][68], s_dx[16][68], s_B[16][68], s_C[16][68];
  __shared__ float s_z[64][17], s_t[64][17];
  __shared__ float s_yp[16][16][17];   // [d][n][step] partials, padded
  float h = H[((b*64 + dg)*256 + g*16 + n) + NSTATE*c];
  int lbase = c*CHUNK;
  for (int l0 = 0; l0 < CHUNK; l0 += 64) {
    {
      int li = tid >> 2, dd = (tid & 3) * 4;
      size_t row = (size_t)b*LL + lbase + l0 + li;
      float4 vd = *(const float4*)(delta + row*DI + d0 + dd);
      float4 vx = *(const float4*)(xs    + row*DI + d0 + dd);
      float4 vz = *(const float4*)(xz    + row*2*DI + DI + d0 + dd);
      float4 vB = *(const float4*)(dbc   + row*64 + 32 + dd);
      float4 vC = *(const float4*)(dbc   + row*64 + 48 + dd);
      float4 vD = *(const float4*)(D_skip + d0 + dd);
      s_d [dd+0][li]=vd.x; s_d [dd+1][li]=vd.y; s_d [dd+2][li]=vd.z; s_d [dd+3][li]=vd.w;
      s_dx[dd+0][li]=vd.x*vx.x; s_dx[dd+1][li]=vd.y*vx.y; s_dx[dd+2][li]=vd.z*vx.z; s_dx[dd+3][li]=vd.w*vx.w;
      s_B [dd+0][li]=vB.x; s_B [dd+1][li]=vB.y; s_B [dd+2][li]=vB.z; s_B [dd+3][li]=vB.w;
      s_C [dd+0][li]=vC.x; s_C [dd+1][li]=vC.y; s_C [dd+2][li]=vC.z; s_C [dd+3][li]=vC.w;
      float4 sz;
      sz.x = vz.x / (1.f + __expf(-vz.x));
      sz.y = vz.y / (1.f + __expf(-vz.y));
      sz.z = vz.z / (1.f + __expf(-vz.z));
      sz.w = vz.w / (1.f + __expf(-vz.w));
      s_z[li][dd+0]=sz.x; s_z[li][dd+1]=sz.y; s_z[li][dd+2]=sz.z; s_z[li][dd+3]=sz.w;
      s_t[li][dd+0]=vx.x*vD.x*sz.x; s_t[li][dd+1]=vx.y*vD.y*sz.y;
      s_t[li][dd+2]=vx.z*vD.z*sz.z; s_t[li][dd+3]=vx.w*vD.w*sz.w;
    }
    __syncthreads();
    #pragma unroll
    for (int sub = 0; sub < 4; ++sub) {
      #pragma unroll
      for (int q4 = 0; q4 < 16; q4 += 4) {
        int li = sub*16 + q4;
        float4 vd  = *(const float4*)&s_d[g][li];
        float4 vdx = *(const float4*)&s_dx[g][li];
        float4 vB  = *(const float4*)&s_B[n][li];
        float4 vC  = *(const float4*)&s_C[n][li];
        float dA;
        dA = exp2f(vd.x*Adn2); h = fmaf(dA, h, vdx.x*vB.x); s_yp[g][n][q4+0] = h*vC.x;
        dA = exp2f(vd.y*Adn2); h = fmaf(dA, h, vdx.y*vB.y); s_yp[g][n][q4+1] = h*vC.y;
        dA = exp2f(vd.z*Adn2); h = fmaf(dA, h, vdx.z*vB.z); s_yp[g][n][q4+2] = h*vC.z;
        dA = exp2f(vd.w*Adn2); h = fmaf(dA, h, vdx.w*vB.w); s_yp[g][n][q4+3] = h*vC.w;
      }
      __syncthreads();
      {
        int q_r = tid & 15, g_r = tid >> 4;
        float y = 0.f;
        #pragma unroll
        for (int nn = 0; nn < 16; ++nn) y += s_yp[g_r][nn][q_r];
        int lis = sub*16 + q_r;
        float v = y * s_z[lis][g_r] + s_t[lis][g_r];
        ymulb[((size_t)b*LL + lbase + l0 + lis)*DI + d0 + g_r] = f2bf(v);
      }
      __syncthreads();
    }
  }
}

extern "C" void kernel_launch(void* const* d_in, const int* in_sizes, int n_in,
                              void* d_out, int out_size, void* d_ws, size_t ws_size,
                              hipStream_t stream) {
  const float* x         = (const float*)d_in[0];
  const float* in_proj_w = (const float*)d_in[1];
  const float* conv_w    = (const float*)d_in[2];
  const float* conv_b    = (const float*)d_in[3];
  const float* x_proj_w  = (const float*)d_in[4];
  const float* dt_proj_w = (const float*)d_in[5];
  const float* dt_proj_b = (const float*)d_in[6];
  const float* A_log     = (const float*)d_in[7];
  const float* D_skip    = (const float*)d_in[8];
  const float* out_proj_w= (const float*)d_in[9];
  const float* moe_w1    = (const float*)d_in[10];
  const float* moe_b1    = (const float*)d_in[11];
  const float* moe_w2    = (const float*)d_in[12];
  const float* moe_b2    = (const float*)d_in[13];
  float* out = (float*)d_out;

  // Arena in floats; total ~23.2M floats = 93 MB.
  float* ws = (float*)d_ws;
  float*          h1    = ws;                                  // 2M f
  unsigned short* h1b   = (unsigned short*)(h1 + 2097152);     // 1M f region
  float*          xz    = (float*)((float*)h1b + 1048576);     // 8M f
  float*          xs    = xz + 8388608;                        // 4M f
  unsigned short* xsb   = (unsigned short*)(xs + 4194304);     // 2M f region
  float*          delta = (float*)((float*)xsb + 2097152);     // 4M f
  float*          dbc   = delta + 4194304;                     // 256K f
  unsigned short* dbcb  = (unsigned short*)(dbc + 262144);     // 128K f region
  float*          wb    = (float*)dbcb + 131072;
  unsigned short* inpb  = (unsigned short*)wb;                 // 512K f (1M elts)
  unsigned short* xpjb  = (unsigned short*)(wb + 524288);      // 32K f
  unsigned short* dtpb  = (unsigned short*)(wb + 524288+32768);        // 16K f
  unsigned short* outpb = (unsigned short*)(wb + 524288+32768+16384);  // 256K f
  unsigned short* w1b   = (unsigned short*)(wb + 524288+32768+16384+262144);        // 512K f
  unsigned short* w2cb  = (unsigned short*)(wb + 524288+32768+16384+262144+524288); // 512K f
  float*          b2avg = wb + 524288+32768+16384+262144+524288+524288;             // 512 f
  // Overlays:
  unsigned short* ymulb = xsb;                                  // scan out (xsb dead after x_proj)
  float*          h2    = xs;                                   // (xs dead after scan)
  unsigned short* h2lnb = (unsigned short*)(xz + 4194304);      // in xz region
  unsigned short* acatb = (unsigned short*)xz;                  // in xz region
  // Scan scratch overlays (dead after in_proj GEMM):
  float*          Pbuf  = (float*)inpb;                         // 512K f (2MB)
  float*          Qbuf  = (float*)h1b;                          // first 2MB of h1b region
  float*          Hbuf  = (float*)h1b + 524288;                 // second 2MB of h1b region

  // 0) weight conversions (bf16) + w2 repack
  f2b4_kernel<<<(1048576/4 + 255)/256, 256, 0, stream>>>(in_proj_w, inpb, 1048576/4);
  f2b4_kernel<<<(65536/4   + 255)/256, 256, 0, stream>>>(x_proj_w,  xpjb, 65536/4);
  f2b4_kernel<<<(32768/4   + 255)/256, 256, 0, stream>>>(dt_proj_w, dtpb, 32768/4);
  f2b4_kernel<<<(524288/4  + 255)/256, 256, 0, stream>>>(out_proj_w,outpb,524288/4);
  f2b4_kernel<<<(1048576/4 + 255)/256, 256, 0, stream>>>(moe_w1,    w1b,  1048576/4);
  repack_kernel<<<(DM*2*DI + 255)/256, 256, 0, stream>>>(moe_w2, moe_b2, w2cb, b2avg);
  // 1) h1 = LN(x)  (fp32 + bf16)
  ln_kernel<<<MM, 256, 0, stream>>>(x, h1, h1b);
  // 2) xz = h1 @ in_proj_w^T   (4096 x 2048, K=512)
  gemm_mfma<128,128,2,2,4,4,ACT_NONE,true,false><<<dim3(16,32), 256, 0, stream>>>(
      h1b, DM, inpb, DM, nullptr, nullptr, 0, xz, nullptr, 2*DI, DM, 1.f);
  // 3) xs = silu(causal depthwise conv(xc) + b)  (fp32 + bf16)
  conv_silu_kernel<<<(MM*DI)/256, 256, 0, stream>>>(xz, conv_w, conv_b, xs, xsb);
  // 4) dbc = xs @ x_proj_w^T   (4096 x 64, K=1024)  (fp32 + bf16)
  gemm_mfma<128,64,4,1,2,4,ACT_NONE,true,true><<<dim3(1,32), 256, 0, stream>>>(
      xsb, DI, xpjb, DI, nullptr, nullptr, 0, dbc, dbcb, 64, DI, 1.f);
  // 5) delta = softplus(dt @ dt_proj_w^T + b)   (4096 x 1024, K=32)
  gemm_mfma<128,128,2,2,4,4,ACT_SP,true,false><<<dim3(8,32), 256, 0, stream>>>(
      dbcb, 64, dtpb, DTR, dt_proj_b, nullptr, 0, delta, nullptr, DI, DTR, 1.f);
  // 6) chunked selective scan -> ymulb (bf16)
  scan_p1<<<BB*64*NCH, 256, 0, stream>>>(delta, xs, dbc, A_log, Pbuf, Qbuf);
  scan_stitch<<<NSTATE/256, 256, 0, stream>>>(Pbuf, Qbuf, Hbuf);
  scan_p2<<<BB*64*NCH, 256, 0, stream>>>(delta, xs, xz, dbc, A_log, D_skip, Hbuf, ymulb);
  // 7) h2 = ymul @ out_proj_w^T + h1   (4096 x 512, K=1024)
  gemm_mfma<128,128,2,2,4,4,ACT_NONE,true,false><<<dim3(4,32), 256, 0, stream>>>(
      ymulb, DI, outpb, DI, nullptr, h1, DM, h2, nullptr, DM, DI, 1.f);
  // 8) h2lnb = LN(h2) (bf16 only)
  ln_kernel<<<MM, 256, 0, stream>>>(h2, nullptr, h2lnb);
  // 9) acatb = relu(h2ln @ moe_w1cat^T + b1)   (4096 x 2048, K=512) bf16 out
  gemm_mfma<128,128,2,2,4,4,ACT_RELU,false,true><<<dim3(16,32), 256, 0, stream>>>(
      h2lnb, DM, w1b, DM, moe_b1, nullptr, 0, nullptr, acatb, 2*DI, DM, 1.f);
  // 10) out = 0.5*(acat @ w2cat^T) + b2avg + x   (4096 x 512, K=2048)
  gemm_mfma<128,128,2,2,4,4,ACT_NONE,true,false><<<dim3(4,32), 256, 0, stream>>>(
      acatb, 2*DI, w2cb, 2*DI, b2avg, x, DM, out, nullptr, DM, 2*DI, 0.5f);
}

// Round 6
// 225.136 us; speedup vs baseline: 5.1783x; 1.3238x over previous
//
#include <hip/hip_runtime.h>
#include <hip/hip_bf16.h>

// Sizes (match reference)
#define BB 4
#define LL 1024
#define DM 512
#define DI 1024
#define DS 16
#define DTR 32
#define MM (BB*LL)        // 4096 rows

#define ACT_NONE 0
#define ACT_RELU 1
#define ACT_SP   2

#define CHUNK 128
#define NCH (LL/CHUNK)    // 8 chunks
#define NSTATE 65536      // B * DI * DS

typedef __attribute__((ext_vector_type(8))) __bf16 bf16x8;
typedef __attribute__((ext_vector_type(8))) unsigned short us8;
typedef __attribute__((ext_vector_type(4))) float f32x4;

__device__ __forceinline__ unsigned short f2bf(float f) {
  union { float f; unsigned int u; } a; a.f = f;
  unsigned int r = a.u + 0x7fffu + ((a.u >> 16) & 1u);
  return (unsigned short)(r >> 16);
}

__device__ __forceinline__ bf16x8 ld_frag(const unsigned short* p) {
  us8 s = *(const us8*)p;
  return __builtin_bit_cast(bf16x8, s);
}

// async global->LDS, 16B per lane. LDS dest must be wave-uniform base + lane*16.
__device__ __forceinline__ void gload16(const void* g, void* l) {
  __builtin_amdgcn_global_load_lds(
      (const __attribute__((address_space(1))) void*)g,
      (__attribute__((address_space(3))) void*)l, 16, 0, 0);
}

// ---------------- f32 -> bf16 copy (vectorized x4) ----------------
__global__ __launch_bounds__(256) void f2b4_kernel(const float* __restrict__ in,
                                                   unsigned short* __restrict__ out, int n4) {
  int i = blockIdx.x * 256 + threadIdx.x;
  if (i < n4) {
    float4 v = ((const float4*)in)[i];
    ushort4 o;
    o.x = f2bf(v.x); o.y = f2bf(v.y); o.z = f2bf(v.z); o.w = f2bf(v.w);
    ((ushort4*)out)[i] = o;
  }
}

// ---------------- MoE W2 repack to bf16 ----------------
__global__ __launch_bounds__(256) void repack_kernel(
    const float* __restrict__ moe_w2, const float* __restrict__ moe_b2,
    unsigned short* __restrict__ w2catb, float* __restrict__ b2avg)
{
  int idx = blockIdx.x * 256 + threadIdx.x;
  if (idx < DM * 2*DI) {
    int nrow = idx >> 11;
    int t = idx & (2*DI - 1);
    int e = t >> 10;
    int k = t & (DI - 1);
    w2catb[idx] = f2bf(moe_w2[((size_t)e*DM + nrow)*DI + k]);
  }
  if (idx < DM) b2avg[idx] = 0.5f * (moe_b2[idx] + moe_b2[DM + idx]);
}

// ---------------- LayerNorm ----------------
__global__ __launch_bounds__(256) void ln_kernel(const float* __restrict__ in,
                                                 float* __restrict__ outf,
                                                 unsigned short* __restrict__ outb) {
  int row = blockIdx.x;
  const float* p = in + (size_t)row * DM;
  float2 v = ((const float2*)p)[threadIdx.x];
  float s  = v.x + v.y;
  float ss = v.x*v.x + v.y*v.y;
  for (int o = 32; o; o >>= 1) { s += __shfl_down(s, o); ss += __shfl_down(ss, o); }
  __shared__ float red[8];
  int wid = threadIdx.x >> 6, lane = threadIdx.x & 63;
  if (lane == 0) { red[wid] = s; red[4+wid] = ss; }
  __syncthreads();
  s  = red[0]+red[1]+red[2]+red[3];
  ss = red[4]+red[5]+red[6]+red[7];
  float mu = s * (1.f/DM);
  float var = ss * (1.f/DM) - mu*mu;
  float rstd = rsqrtf(var + 1e-5f);
  float2 o2; o2.x = (v.x-mu)*rstd; o2.y = (v.y-mu)*rstd;
  if (outf) ((float2*)(outf + (size_t)row*DM))[threadIdx.x] = o2;
  if (outb) {
    ushort2 u; u.x = f2bf(o2.x); u.y = f2bf(o2.y);
    ((ushort2*)(outb + (size_t)row*DM))[threadIdx.x] = u;
  }
}

// ---------------- bf16 MFMA GEMM: C = act(scale*A@B^T + bias) + res ---------
// Double-buffered LDS via global_load_lds; BK=64 path uses XOR bank swizzle
// (pre-swizzled global source + swizzled ds_read, linear LDS dest).
// 1D grid, XCD-chunked block swizzle; row-major work decode (col fastest).
template<int BM, int BN, int BK, int WR, int WC, int FM, int FN, int ACT,
         bool OUTF, bool OUTB, bool DBUF>
__global__ __launch_bounds__(256) void gemm_mfma(
    const unsigned short* __restrict__ A, int lda,
    const unsigned short* __restrict__ B, int ldb,
    const float* __restrict__ bias,
    const float* __restrict__ res, int ldres,
    float* __restrict__ Cf, unsigned short* __restrict__ Cb, int ldc,
    int K, float scale, int nbx)
{
  static_assert(WR*WC == 4 && WR*FM*16 == BM && WC*FN*16 == BN, "geom");
  constexpr int ATILE = BM*BK, BTILE = BN*BK;       // elements
  constexpr int AL = ATILE/2048, BL = BTILE/2048;   // gload16 per thread
  constexpr bool SWZ = (BK == 64);
  __shared__ unsigned short As[(DBUF?2:1)*ATILE];
  __shared__ unsigned short Bs[(DBUF?2:1)*BTILE];
  const int tid = threadIdx.x;
  const int nwg = gridDim.x;
  const int bid = blockIdx.x;
  const int cpx = nwg >> 3;
  const int wid = ((nwg & 7) == 0) ? ((bid & 7)*cpx + (bid >> 3)) : bid;
  const int bm = (wid / nbx) * BM;
  const int bn = (wid % nbx) * BN;
  const int w = tid >> 6, lane = tid & 63;
  const int wr = w / WC, wc = w % WC;
  const int rl = lane & 15, kg = lane >> 4;

  auto stage = [&](int buf, int k0) {
    #pragma unroll
    for (int it = 0; it < AL; ++it) {
      int o = (it*256 + tid) * 16;                    // byte offset in tile
      int os = SWZ ? (o ^ (((o>>7)&7)<<4)) : o;       // source-side swizzle
      int e = os >> 1;
      int r = e / BK, c = e % BK;
      gload16(A + (size_t)(bm + r)*lda + k0 + c, (char*)As + buf*ATILE*2 + o);
    }
    #pragma unroll
    for (int it = 0; it < BL; ++it) {
      int o = (it*256 + tid) * 16;
      int os = SWZ ? (o ^ (((o>>7)&7)<<4)) : o;
      int e = os >> 1;
      int r = e / BK, c = e % BK;
      gload16(B + (size_t)(bn + r)*ldb + k0 + c, (char*)Bs + buf*BTILE*2 + o);
    }
  };

  f32x4 acc[FM][FN];
  #pragma unroll
  for (int m = 0; m < FM; ++m)
    #pragma unroll
    for (int n = 0; n < FN; ++n) { f32x4 z = {0.f,0.f,0.f,0.f}; acc[m][n] = z; }

  auto compute = [&](int buf) {
    #pragma unroll
    for (int kk = 0; kk < BK/32; ++kk) {
      bf16x8 af[FM], bfv[FN];
      #pragma unroll
      for (int m = 0; m < FM; ++m) {
        int byte = ((wr*FM*16 + m*16 + rl)*BK + kk*32 + kg*8) * 2;
        if (SWZ) byte ^= ((byte>>7)&7)<<4;
        af[m] = ld_frag((const unsigned short*)((const char*)As + buf*ATILE*2 + byte));
      }
      #pragma unroll
      for (int n = 0; n < FN; ++n) {
        int byte = ((wc*FN*16 + n*16 + rl)*BK + kk*32 + kg*8) * 2;
        if (SWZ) byte ^= ((byte>>7)&7)<<4;
        bfv[n] = ld_frag((const unsigned short*)((const char*)Bs + buf*BTILE*2 + byte));
      }
      #pragma unroll
      for (int m = 0; m < FM; ++m)
        #pragma unroll
        for (int n = 0; n < FN; ++n)
          acc[m][n] = __builtin_amdgcn_mfma_f32_16x16x32_bf16(af[m], bfv[n], acc[m][n], 0, 0, 0);
    }
  };

  if (DBUF) {
    stage(0, 0);
    const int nk = K / BK;
    for (int it = 0; it < nk; ++it) {
      __syncthreads();                 // drains vmcnt: buf (it&1) ready; prev reads done
      if (it + 1 < nk) stage((it&1)^1, (it+1)*BK);
      compute(it & 1);
    }
  } else {
    for (int k0 = 0; k0 < K; k0 += BK) {
      stage(0, k0);
      __syncthreads();
      compute(0);
      __syncthreads();
    }
  }

  // epilogue: C/D mapping col=lane&15, row=(lane>>4)*4+reg
  #pragma unroll
  for (int m = 0; m < FM; ++m) {
    int row = bm + wr*FM*16 + m*16 + kg*4;
    #pragma unroll
    for (int n = 0; n < FN; ++n) {
      int col = bn + wc*FN*16 + n*16 + rl;
      float bv = bias ? bias[col] : 0.f;
      #pragma unroll
      for (int j = 0; j < 4; ++j) {
        float v = acc[m][n][j] * scale + bv;
        if (ACT == ACT_RELU) v = fmaxf(v, 0.f);
        if (ACT == ACT_SP)   v = fmaxf(v, 0.f) + log1pf(__expf(-fabsf(v)));
        if (res) v += res[(size_t)(row + j)*ldres + col];
        size_t off = (size_t)(row + j)*ldc + col;
        if (OUTF) Cf[off] = v;
        if (OUTB) Cb[off] = f2bf(v);
      }
    }
  }
}

// ---------------- Depthwise causal conv (k=4) + SiLU --------------------
__global__ __launch_bounds__(256) void conv_silu_kernel(
    const float* __restrict__ xz, const float* __restrict__ conv_w,
    const float* __restrict__ conv_b, float* __restrict__ xs,
    unsigned short* __restrict__ xsb)
{
  int gid = blockIdx.x * 256 + threadIdx.x;   // B*L*DI = 4M
  int d = gid & (DI-1);
  int l = (gid >> 10) & (LL-1);
  int b = gid >> 20;
  const float* w = conv_w + d*4;
  float s = conv_b[d];
  size_t base = (size_t)b * LL * 2*DI + d;
  #pragma unroll
  for (int k = 0; k < 4; ++k) {
    int ll = l - 3 + k;
    if (ll >= 0) s = fmaf(w[k], xz[base + (size_t)ll * 2*DI], s);
  }
  float sig = 1.f / (1.f + __expf(-s));
  float v = s * sig;
  xs[gid] = v;
  xsb[gid] = f2bf(v);
}

// ============ Chunked selective scan =========================================
__global__ __launch_bounds__(256) void scan_p1(
    const float* __restrict__ delta,
    const float* __restrict__ xs,
    const float* __restrict__ dbc,
    const float* __restrict__ A_log,
    float* __restrict__ P, float* __restrict__ Q)
{
  int blk = blockIdx.x;
  int c  = blk & (NCH-1);
  int dg = (blk >> 3) & 63;
  int b  = blk >> 9;
  int tid = threadIdx.x;
  int g = tid >> 4, n = tid & 15;
  int d0 = dg*16;
  float Adn2 = -__expf(A_log[(d0+g)*DS + n]) * 1.44269504f;
  __shared__ float s_d[16][68], s_dx[16][68], s_B[16][68];
  float h = 0.f, S = 0.f;
  int lbase = c*CHUNK;
  for (int l0 = 0; l0 < CHUNK; l0 += 64) {
    {
      int li = tid >> 2, dd = (tid & 3) * 4;
      size_t row = (size_t)b*LL + lbase + l0 + li;
      float4 vd = *(const float4*)(delta + row*DI + d0 + dd);
      float4 vx = *(const float4*)(xs    + row*DI + d0 + dd);
      float4 vB = *(const float4*)(dbc   + row*64 + 32 + dd);
      s_d [dd+0][li]=vd.x; s_d [dd+1][li]=vd.y; s_d [dd+2][li]=vd.z; s_d [dd+3][li]=vd.w;
      s_dx[dd+0][li]=vd.x*vx.x; s_dx[dd+1][li]=vd.y*vx.y; s_dx[dd+2][li]=vd.z*vx.z; s_dx[dd+3][li]=vd.w*vx.w;
      s_B [dd+0][li]=vB.x; s_B [dd+1][li]=vB.y; s_B [dd+2][li]=vB.z; s_B [dd+3][li]=vB.w;
    }
    __syncthreads();
    #pragma unroll
    for (int q4 = 0; q4 < 64; q4 += 4) {
      float4 vd  = *(const float4*)&s_d[g][q4];
      float4 vdx = *(const float4*)&s_dx[g][q4];
      float4 vB  = *(const float4*)&s_B[n][q4];
      float dA;
      dA = exp2f(vd.x*Adn2); h = fmaf(dA, h, vdx.x*vB.x); S += vd.x;
      dA = exp2f(vd.y*Adn2); h = fmaf(dA, h, vdx.y*vB.y); S += vd.y;
      dA = exp2f(vd.z*Adn2); h = fmaf(dA, h, vdx.z*vB.z); S += vd.z;
      dA = exp2f(vd.w*Adn2); h = fmaf(dA, h, vdx.w*vB.w); S += vd.w;
    }
    __syncthreads();
  }
  int base = ((b*64 + dg)*256 + g*16 + n) + NSTATE*c;
  P[base] = exp2f(S * Adn2);
  Q[base] = h;
}

__global__ __launch_bounds__(256) void scan_stitch(
    const float* __restrict__ P, const float* __restrict__ Q,
    float* __restrict__ H)
{
  int t = blockIdx.x * 256 + threadIdx.x;   // 65536
  float h = 0.f;
  #pragma unroll
  for (int c = 0; c < NCH; ++c) {
    H[t + NSTATE*c] = h;
    h = fmaf(P[t + NSTATE*c], h, Q[t + NSTATE*c]);
  }
}

__global__ __launch_bounds__(256) void scan_p2(
    const float* __restrict__ delta,
    const float* __restrict__ xs,
    const float* __restrict__ xz,     // read z half
    const float* __restrict__ dbc,    // Bm at 32+n, Cm at 48+n
    const float* __restrict__ A_log,
    const float* __restrict__ D_skip,
    const float* __restrict__ H,
    unsigned short* __restrict__ ymulb)
{
  int blk = blockIdx.x;
  int c  = blk & (NCH-1);
  int dg = (blk >> 3) & 63;
  int b  = blk >> 9;
  int tid = threadIdx.x;
  int g = tid >> 4, n = tid & 15;
  int d0 = dg*16;
  float Adn2 = -__expf(A_log[(d0+g)*DS + n]) * 1.44269504f;
  __shared__ float s_d[16][68], s_dx[16][68], s_B[16][68], s_C[16][68];
  __shared__ float s_z[64][17], s_t[64][17];
  __shared__ float s_yp[16][16][17];   // [d][n][step] partials, padded
  float h = H[((b*64 + dg)*256 + g*16 + n) + NSTATE*c];
  int lbase = c*CHUNK;
  for (int l0 = 0; l0 < CHUNK; l0 += 64) {
    {
      int li = tid >> 2, dd = (tid & 3) * 4;
      size_t row = (size_t)b*LL + lbase + l0 + li;
      float4 vd = *(const float4*)(delta + row*DI + d0 + dd);
      float4 vx = *(const float4*)(xs    + row*DI + d0 + dd);
      float4 vz = *(const float4*)(xz    + row*2*DI + DI + d0 + dd);
      float4 vB = *(const float4*)(dbc   + row*64 + 32 + dd);
      float4 vC = *(const float4*)(dbc   + row*64 + 48 + dd);
      float4 vD = *(const float4*)(D_skip + d0 + dd);
      s_d [dd+0][li]=vd.x; s_d [dd+1][li]=vd.y; s_d [dd+2][li]=vd.z; s_d [dd+3][li]=vd.w;
      s_dx[dd+0][li]=vd.x*vx.x; s_dx[dd+1][li]=vd.y*vx.y; s_dx[dd+2][li]=vd.z*vx.z; s_dx[dd+3][li]=vd.w*vx.w;
      s_B [dd+0][li]=vB.x; s_B [dd+1][li]=vB.y; s_B [dd+2][li]=vB.z; s_B [dd+3][li]=vB.w;
      s_C [dd+0][li]=vC.x; s_C [dd+1][li]=vC.y; s_C [dd+2][li]=vC.z; s_C [dd+3][li]=vC.w;
      float4 sz;
      sz.x = vz.x / (1.f + __expf(-vz.x));
      sz.y = vz.y / (1.f + __expf(-vz.y));
      sz.z = vz.z / (1.f + __expf(-vz.z));
      sz.w = vz.w / (1.f + __expf(-vz.w));
      s_z[li][dd+0]=sz.x; s_z[li][dd+1]=sz.y; s_z[li][dd+2]=sz.z; s_z[li][dd+3]=sz.w;
      s_t[li][dd+0]=vx.x*vD.x*sz.x; s_t[li][dd+1]=vx.y*vD.y*sz.y;
      s_t[li][dd+2]=vx.z*vD.z*sz.z; s_t[li][dd+3]=vx.w*vD.w*sz.w;
    }
    __syncthreads();
    #pragma unroll
    for (int sub = 0; sub < 4; ++sub) {
      #pragma unroll
      for (int q4 = 0; q4 < 16; q4 += 4) {
        int li = sub*16 + q4;
        float4 vd  = *(const float4*)&s_d[g][li];
        float4 vdx = *(const float4*)&s_dx[g][li];
        float4 vB  = *(const float4*)&s_B[n][li];
        float4 vC  = *(const float4*)&s_C[n][li];
        float dA;
        dA = exp2f(vd.x*Adn2); h = fmaf(dA, h, vdx.x*vB.x); s_yp[g][n][q4+0] = h*vC.x;
        dA = exp2f(vd.y*Adn2); h = fmaf(dA, h, vdx.y*vB.y); s_yp[g][n][q4+1] = h*vC.y;
        dA = exp2f(vd.z*Adn2); h = fmaf(dA, h, vdx.z*vB.z); s_yp[g][n][q4+2] = h*vC.z;
        dA = exp2f(vd.w*Adn2); h = fmaf(dA, h, vdx.w*vB.w); s_yp[g][n][q4+3] = h*vC.w;
      }
      __syncthreads();
      {
        int q_r = tid & 15, g_r = tid >> 4;
        float y = 0.f;
        #pragma unroll
        for (int nn = 0; nn < 16; ++nn) y += s_yp[g_r][nn][q_r];
        int lis = sub*16 + q_r;
        float v = y * s_z[lis][g_r] + s_t[lis][g_r];
        ymulb[((size_t)b*LL + lbase + l0 + lis)*DI + d0 + g_r] = f2bf(v);
      }
      __syncthreads();
    }
  }
}

extern "C" void kernel_launch(void* const* d_in, const int* in_sizes, int n_in,
                              void* d_out, int out_size, void* d_ws, size_t ws_size,
                              hipStream_t stream) {
  const float* x         = (const float*)d_in[0];
  const float* in_proj_w = (const float*)d_in[1];
  const float* conv_w    = (const float*)d_in[2];
  const float* conv_b    = (const float*)d_in[3];
  const float* x_proj_w  = (const float*)d_in[4];
  const float* dt_proj_w = (const float*)d_in[5];
  const float* dt_proj_b = (const float*)d_in[6];
  const float* A_log     = (const float*)d_in[7];
  const float* D_skip    = (const float*)d_in[8];
  const float* out_proj_w= (const float*)d_in[9];
  const float* moe_w1    = (const float*)d_in[10];
  const float* moe_b1    = (const float*)d_in[11];
  const float* moe_w2    = (const float*)d_in[12];
  const float* moe_b2    = (const float*)d_in[13];
  float* out = (float*)d_out;

  // Arena in floats; total ~23.2M floats = 93 MB.
  float* ws = (float*)d_ws;
  float*          h1    = ws;                                  // 2M f
  unsigned short* h1b   = (unsigned short*)(h1 + 2097152);     // 1M f region
  float*          xz    = (float*)((float*)h1b + 1048576);     // 8M f
  float*          xs    = xz + 8388608;                        // 4M f
  unsigned short* xsb   = (unsigned short*)(xs + 4194304);     // 2M f region
  float*          delta = (float*)((float*)xsb + 2097152);     // 4M f
  float*          dbc   = delta + 4194304;                     // 256K f
  unsigned short* dbcb  = (unsigned short*)(dbc + 262144);     // 128K f region
  float*          wb    = (float*)dbcb + 131072;
  unsigned short* inpb  = (unsigned short*)wb;                 // 512K f (1M elts)
  unsigned short* xpjb  = (unsigned short*)(wb + 524288);      // 32K f
  unsigned short* dtpb  = (unsigned short*)(wb + 524288+32768);        // 16K f
  unsigned short* outpb = (unsigned short*)(wb + 524288+32768+16384);  // 256K f
  unsigned short* w1b   = (unsigned short*)(wb + 524288+32768+16384+262144);        // 512K f
  unsigned short* w2cb  = (unsigned short*)(wb + 524288+32768+16384+262144+524288); // 512K f
  float*          b2avg = wb + 524288+32768+16384+262144+524288+524288;             // 512 f
  // Overlays:
  unsigned short* ymulb = xsb;                                  // scan out (xsb dead after x_proj)
  float*          h2    = xs;                                   // (xs dead after scan)
  unsigned short* h2lnb = (unsigned short*)(xz + 4194304);      // in xz region
  unsigned short* acatb = (unsigned short*)xz;                  // in xz region
  // Scan scratch overlays (dead after in_proj GEMM):
  float*          Pbuf  = (float*)inpb;                         // 2MB
  float*          Qbuf  = (float*)h1b;                          // first 2MB of h1b region
  float*          Hbuf  = (float*)h1b + 524288;                 // second 2MB of h1b region

  // 0) weight conversions (bf16) + w2 repack
  f2b4_kernel<<<(1048576/4 + 255)/256, 256, 0, stream>>>(in_proj_w, inpb, 1048576/4);
  f2b4_kernel<<<(65536/4   + 255)/256, 256, 0, stream>>>(x_proj_w,  xpjb, 65536/4);
  f2b4_kernel<<<(32768/4   + 255)/256, 256, 0, stream>>>(dt_proj_w, dtpb, 32768/4);
  f2b4_kernel<<<(524288/4  + 255)/256, 256, 0, stream>>>(out_proj_w,outpb,524288/4);
  f2b4_kernel<<<(1048576/4 + 255)/256, 256, 0, stream>>>(moe_w1,    w1b,  1048576/4);
  repack_kernel<<<(DM*2*DI + 255)/256, 256, 0, stream>>>(moe_w2, moe_b2, w2cb, b2avg);
  // 1) h1 = LN(x)  (fp32 + bf16)
  ln_kernel<<<MM, 256, 0, stream>>>(x, h1, h1b);
  // 2) xz = h1 @ in_proj_w^T   (4096 x 2048, K=512)  128x128xBK64, 512 blocks
  gemm_mfma<128,128,64,2,2,4,4,ACT_NONE,true,false,true><<<512, 256, 0, stream>>>(
      h1b, DM, inpb, DM, nullptr, nullptr, 0, xz, nullptr, 2*DI, DM, 1.f, 16);
  // 3) xs = silu(causal depthwise conv(xc) + b)  (fp32 + bf16)
  conv_silu_kernel<<<(MM*DI)/256, 256, 0, stream>>>(xz, conv_w, conv_b, xs, xsb);
  // 4) dbc = xs @ x_proj_w^T   (4096 x 64, K=1024)  64x64xBK64, 64 blocks
  gemm_mfma<64,64,64,2,2,2,2,ACT_NONE,true,true,true><<<64, 256, 0, stream>>>(
      xsb, DI, xpjb, DI, nullptr, nullptr, 0, dbc, dbcb, 64, DI, 1.f, 1);
  // 5) delta = softplus(dt @ dt_proj_w^T + b)   (4096 x 1024, K=32) single-buf
  gemm_mfma<128,128,32,2,2,4,4,ACT_SP,true,false,false><<<256, 256, 0, stream>>>(
      dbcb, 64, dtpb, DTR, dt_proj_b, nullptr, 0, delta, nullptr, DI, DTR, 1.f, 8);
  // 6) chunked selective scan -> ymulb (bf16)
  scan_p1<<<BB*64*NCH, 256, 0, stream>>>(delta, xs, dbc, A_log, Pbuf, Qbuf);
  scan_stitch<<<NSTATE/256, 256, 0, stream>>>(Pbuf, Qbuf, Hbuf);
  scan_p2<<<BB*64*NCH, 256, 0, stream>>>(delta, xs, xz, dbc, A_log, D_skip, Hbuf, ymulb);
  // 7) h2 = ymul @ out_proj_w^T + h1   (4096 x 512, K=1024) 64x64xBK64, 512 blocks
  gemm_mfma<64,64,64,2,2,2,2,ACT_NONE,true,false,true><<<512, 256, 0, stream>>>(
      ymulb, DI, outpb, DI, nullptr, h1, DM, h2, nullptr, DM, DI, 1.f, 8);
  // 8) h2lnb = LN(h2) (bf16 only)
  ln_kernel<<<MM, 256, 0, stream>>>(h2, nullptr, h2lnb);
  // 9) acatb = relu(h2ln @ moe_w1cat^T + b1)   (4096 x 2048, K=512) 512 blocks
  gemm_mfma<128,128,64,2,2,4,4,ACT_RELU,false,true,true><<<512, 256, 0, stream>>>(
      h2lnb, DM, w1b, DM, moe_b1, nullptr, 0, nullptr, acatb, 2*DI, DM, 1.f, 16);
  // 10) out = 0.5*(acat @ w2cat^T) + b2avg + x   (4096 x 512, K=2048) 512 blocks
  gemm_mfma<64,64,64,2,2,2,2,ACT_NONE,true,false,true><<<512, 256, 0, stream>>>(
      acatb, 2*DI, w2cb, 2*DI, b2avg, x, DM, out, nullptr, DM, 2*DI, 0.5f, 8);
}

// Round 7
// 221.397 us; speedup vs baseline: 5.2657x; 1.0169x over previous
//
#include <hip/hip_runtime.h>
#include <hip/hip_bf16.h>

// Sizes (match reference)
#define BB 4
#define LL 1024
#define DM 512
#define DI 1024
#define DS 16
#define DTR 32
#define MM (BB*LL)        // 4096 rows

#define ACT_NONE 0
#define ACT_RELU 1
#define ACT_SP   2

#define CHUNK 128
#define NCH (LL/CHUNK)    // 8 chunks
#define NSTATE 65536      // B * DI * DS

typedef __attribute__((ext_vector_type(8))) __bf16 bf16x8;
typedef __attribute__((ext_vector_type(8))) unsigned short us8;
typedef __attribute__((ext_vector_type(4))) float f32x4;

__device__ __forceinline__ unsigned short f2bf(float f) {
  union { float f; unsigned int u; } a; a.f = f;
  unsigned int r = a.u + 0x7fffu + ((a.u >> 16) & 1u);
  return (unsigned short)(r >> 16);
}
__device__ __forceinline__ float b2f(unsigned short u) {
  union { unsigned int i; float f; } a; a.i = (unsigned int)u << 16; return a.f;
}

__device__ __forceinline__ bf16x8 ld_frag(const unsigned short* p) {
  us8 s = *(const us8*)p;
  return __builtin_bit_cast(bf16x8, s);
}

// async global->LDS, 16B per lane. LDS dest must be wave-uniform base + lane*16.
__device__ __forceinline__ void gload16(const void* g, void* l) {
  __builtin_amdgcn_global_load_lds(
      (const __attribute__((address_space(1))) void*)g,
      (__attribute__((address_space(3))) void*)l, 16, 0, 0);
}

// ---------------- Fused weight prep: all f32->bf16 conversions + w2 repack ---
__global__ __launch_bounds__(256) void prep_kernel(
    const float* __restrict__ in_proj_w, const float* __restrict__ x_proj_w,
    const float* __restrict__ dt_proj_w, const float* __restrict__ out_proj_w,
    const float* __restrict__ moe_w1,    const float* __restrict__ moe_w2,
    const float* __restrict__ moe_b2,
    unsigned short* __restrict__ inpb,  unsigned short* __restrict__ xpjb,
    unsigned short* __restrict__ dtpb,  unsigned short* __restrict__ outpb,
    unsigned short* __restrict__ w1b,   unsigned short* __restrict__ w2cb,
    float* __restrict__ b2avg)
{
  int i = blockIdx.x * 256 + threadIdx.x;   // 262144 threads
  int i4 = i * 4;
  auto cvt4 = [&](const float* src, unsigned short* dst) {
    float4 v = ((const float4*)src)[i];
    ushort4 o; o.x = f2bf(v.x); o.y = f2bf(v.y); o.z = f2bf(v.z); o.w = f2bf(v.w);
    ((ushort4*)dst)[i] = o;
  };
  if (i4 < 2*DI*DM) cvt4(in_proj_w, inpb);
  if (i4 < 64*DI)   cvt4(x_proj_w, xpjb);
  if (i4 < DI*DTR)  cvt4(dt_proj_w, dtpb);
  if (i4 < DM*DI)   cvt4(out_proj_w, outpb);
  if (i4 < 2*DM*DM*2) cvt4(moe_w1, w1b);   // (2,1024,512) flat = (2048,512) row-major
  if (i4 < DM*2*DI) {
    #pragma unroll
    for (int j = 0; j < 4; ++j) {
      int idx = i4 + j;
      int nrow = idx >> 11;
      int t = idx & (2*DI - 1);
      int e = t >> 10;
      int k = t & (DI - 1);
      w2cb[idx] = f2bf(moe_w2[((size_t)e*DM + nrow)*DI + k]);
    }
  }
  if (i4 < DM) {
    #pragma unroll
    for (int j = 0; j < 4; ++j)
      b2avg[i4+j] = 0.5f * (moe_b2[i4+j] + moe_b2[DM + i4+j]);
  }
}

// ---------------- LayerNorm ----------------
__global__ __launch_bounds__(256) void ln_kernel(const float* __restrict__ in,
                                                 float* __restrict__ outf,
                                                 unsigned short* __restrict__ outb) {
  int row = blockIdx.x;
  const float* p = in + (size_t)row * DM;
  float2 v = ((const float2*)p)[threadIdx.x];
  float s  = v.x + v.y;
  float ss = v.x*v.x + v.y*v.y;
  for (int o = 32; o; o >>= 1) { s += __shfl_down(s, o); ss += __shfl_down(ss, o); }
  __shared__ float red[8];
  int wid = threadIdx.x >> 6, lane = threadIdx.x & 63;
  if (lane == 0) { red[wid] = s; red[4+wid] = ss; }
  __syncthreads();
  s  = red[0]+red[1]+red[2]+red[3];
  ss = red[4]+red[5]+red[6]+red[7];
  float mu = s * (1.f/DM);
  float var = ss * (1.f/DM) - mu*mu;
  float rstd = rsqrtf(var + 1e-5f);
  float2 o2; o2.x = (v.x-mu)*rstd; o2.y = (v.y-mu)*rstd;
  if (outf) ((float2*)(outf + (size_t)row*DM))[threadIdx.x] = o2;
  if (outb) {
    ushort2 u; u.x = f2bf(o2.x); u.y = f2bf(o2.y);
    ((ushort2*)(outb + (size_t)row*DM))[threadIdx.x] = u;
  }
}

// ---------------- bf16 MFMA GEMM: C = act(scale*A@B^T + bias) + res ---------
// Double-buffered LDS via global_load_lds; BK=64 path uses XOR bank swizzle
// (pre-swizzled global source + swizzled ds_read, linear LDS dest).
template<int BM, int BN, int BK, int WR, int WC, int FM, int FN, int ACT,
         bool OUTF, bool OUTB, bool DBUF>
__global__ __launch_bounds__(256) void gemm_mfma(
    const unsigned short* __restrict__ A, int lda,
    const unsigned short* __restrict__ B, int ldb,
    const float* __restrict__ bias,
    const float* __restrict__ res, int ldres,
    float* __restrict__ Cf, unsigned short* __restrict__ Cb, int ldc,
    int K, float scale, int nbx)
{
  static_assert(WR*WC == 4 && WR*FM*16 == BM && WC*FN*16 == BN, "geom");
  constexpr int ATILE = BM*BK, BTILE = BN*BK;       // elements
  constexpr int AL = ATILE/2048, BL = BTILE/2048;   // gload16 per thread
  constexpr bool SWZ = (BK == 64);
  __shared__ unsigned short As[(DBUF?2:1)*ATILE];
  __shared__ unsigned short Bs[(DBUF?2:1)*BTILE];
  const int tid = threadIdx.x;
  const int nwg = gridDim.x;
  const int bid = blockIdx.x;
  const int cpx = nwg >> 3;
  const int wid = ((nwg & 7) == 0) ? ((bid & 7)*cpx + (bid >> 3)) : bid;
  const int bm = (wid / nbx) * BM;
  const int bn = (wid % nbx) * BN;
  const int w = tid >> 6, lane = tid & 63;
  const int wr = w / WC, wc = w % WC;
  const int rl = lane & 15, kg = lane >> 4;

  auto stage = [&](int buf, int k0) {
    #pragma unroll
    for (int it = 0; it < AL; ++it) {
      int o = (it*256 + tid) * 16;                    // byte offset in tile
      int os = SWZ ? (o ^ (((o>>7)&7)<<4)) : o;       // source-side swizzle
      int e = os >> 1;
      int r = e / BK, c = e % BK;
      gload16(A + (size_t)(bm + r)*lda + k0 + c, (char*)As + buf*ATILE*2 + o);
    }
    #pragma unroll
    for (int it = 0; it < BL; ++it) {
      int o = (it*256 + tid) * 16;
      int os = SWZ ? (o ^ (((o>>7)&7)<<4)) : o;
      int e = os >> 1;
      int r = e / BK, c = e % BK;
      gload16(B + (size_t)(bn + r)*ldb + k0 + c, (char*)Bs + buf*BTILE*2 + o);
    }
  };

  f32x4 acc[FM][FN];
  #pragma unroll
  for (int m = 0; m < FM; ++m)
    #pragma unroll
    for (int n = 0; n < FN; ++n) { f32x4 z = {0.f,0.f,0.f,0.f}; acc[m][n] = z; }

  auto compute = [&](int buf) {
    #pragma unroll
    for (int kk = 0; kk < BK/32; ++kk) {
      bf16x8 af[FM], bfv[FN];
      #pragma unroll
      for (int m = 0; m < FM; ++m) {
        int byte = ((wr*FM*16 + m*16 + rl)*BK + kk*32 + kg*8) * 2;
        if (SWZ) byte ^= ((byte>>7)&7)<<4;
        af[m] = ld_frag((const unsigned short*)((const char*)As + buf*ATILE*2 + byte));
      }
      #pragma unroll
      for (int n = 0; n < FN; ++n) {
        int byte = ((wc*FN*16 + n*16 + rl)*BK + kk*32 + kg*8) * 2;
        if (SWZ) byte ^= ((byte>>7)&7)<<4;
        bfv[n] = ld_frag((const unsigned short*)((const char*)Bs + buf*BTILE*2 + byte));
      }
      #pragma unroll
      for (int m = 0; m < FM; ++m)
        #pragma unroll
        for (int n = 0; n < FN; ++n)
          acc[m][n] = __builtin_amdgcn_mfma_f32_16x16x32_bf16(af[m], bfv[n], acc[m][n], 0, 0, 0);
    }
  };

  if (DBUF) {
    stage(0, 0);
    const int nk = K / BK;
    for (int it = 0; it < nk; ++it) {
      __syncthreads();                 // drains vmcnt: buf (it&1) ready; prev reads done
      if (it + 1 < nk) stage((it&1)^1, (it+1)*BK);
      compute(it & 1);
    }
  } else {
    for (int k0 = 0; k0 < K; k0 += BK) {
      stage(0, k0);
      __syncthreads();
      compute(0);
      __syncthreads();
    }
  }

  // epilogue: C/D mapping col=lane&15, row=(lane>>4)*4+reg
  #pragma unroll
  for (int m = 0; m < FM; ++m) {
    int row = bm + wr*FM*16 + m*16 + kg*4;
    #pragma unroll
    for (int n = 0; n < FN; ++n) {
      int col = bn + wc*FN*16 + n*16 + rl;
      float bv = bias ? bias[col] : 0.f;
      #pragma unroll
      for (int j = 0; j < 4; ++j) {
        float v = acc[m][n][j] * scale + bv;
        if (ACT == ACT_RELU) v = fmaxf(v, 0.f);
        if (ACT == ACT_SP)   v = fmaxf(v, 0.f) + log1pf(__expf(-fabsf(v)));
        if (res) v += res[(size_t)(row + j)*ldres + col];
        size_t off = (size_t)(row + j)*ldc + col;
        if (OUTF) Cf[off] = v;
        if (OUTB) Cb[off] = f2bf(v);
      }
    }
  }
}

// ---------------- Depthwise causal conv (k=4) + SiLU, bf16 in/out, x8 vec ---
__global__ __launch_bounds__(256) void conv_silu_kernel(
    const unsigned short* __restrict__ xzb, const float* __restrict__ conv_w,
    const float* __restrict__ conv_b, unsigned short* __restrict__ xsb)
{
  int t = blockIdx.x * 256 + threadIdx.x;   // B*L*DI/8 = 524288
  int d8 = (t & (DI/8 - 1)) * 8;
  int l = (t >> 7) & (LL-1);
  int b = t >> 17;
  size_t base = (size_t)(b*LL) * 2*DI + d8;
  float acc[8];
  #pragma unroll
  for (int j = 0; j < 8; ++j) acc[j] = conv_b[d8+j];
  #pragma unroll
  for (int k = 0; k < 4; ++k) {
    int ll = l - 3 + k;
    if (ll >= 0) {
      us8 v = *(const us8*)(xzb + base + (size_t)ll * 2*DI);
      #pragma unroll
      for (int j = 0; j < 8; ++j)
        acc[j] = fmaf(conv_w[(d8+j)*4 + k], b2f((unsigned short)v[j]), acc[j]);
    }
  }
  us8 o;
  #pragma unroll
  for (int j = 0; j < 8; ++j) {
    float s = acc[j];
    float v = s / (1.f + __expf(-s));
    o[j] = (unsigned short)f2bf(v);
  }
  *(us8*)(xsb + (size_t)((b*LL + l)*DI) + d8) = o;
}

// ============ Chunked selective scan (bf16 activations) ======================
__global__ __launch_bounds__(256) void scan_p1(
    const unsigned short* __restrict__ deltab,
    const unsigned short* __restrict__ xsb,
    const float* __restrict__ dbc,
    const float* __restrict__ A_log,
    float* __restrict__ P, float* __restrict__ Q)
{
  int blk = blockIdx.x;
  int c  = blk & (NCH-1);
  int dg = (blk >> 3) & 63;
  int b  = blk >> 9;
  int tid = threadIdx.x;
  int g = tid >> 4, n = tid & 15;
  int d0 = dg*16;
  float Adn2 = -__expf(A_log[(d0+g)*DS + n]) * 1.44269504f;
  __shared__ float s_d[16][68], s_dx[16][68], s_B[16][68];
  float h = 0.f, S = 0.f;
  int lbase = c*CHUNK;
  for (int l0 = 0; l0 < CHUNK; l0 += 64) {
    {
      int li = tid >> 2, dd = (tid & 3) * 4;
      size_t row = (size_t)b*LL + lbase + l0 + li;
      ushort4 ud = *(const ushort4*)(deltab + row*DI + d0 + dd);
      ushort4 ux = *(const ushort4*)(xsb    + row*DI + d0 + dd);
      float4 vB = *(const float4*)(dbc   + row*64 + 32 + dd);
      float dx_ = b2f(ud.x), dy_ = b2f(ud.y), dz_ = b2f(ud.z), dw_ = b2f(ud.w);
      float xx_ = b2f(ux.x), xy_ = b2f(ux.y), xz_ = b2f(ux.z), xw_ = b2f(ux.w);
      s_d [dd+0][li]=dx_; s_d [dd+1][li]=dy_; s_d [dd+2][li]=dz_; s_d [dd+3][li]=dw_;
      s_dx[dd+0][li]=dx_*xx_; s_dx[dd+1][li]=dy_*xy_; s_dx[dd+2][li]=dz_*xz_; s_dx[dd+3][li]=dw_*xw_;
      s_B [dd+0][li]=vB.x; s_B [dd+1][li]=vB.y; s_B [dd+2][li]=vB.z; s_B [dd+3][li]=vB.w;
    }
    __syncthreads();
    #pragma unroll
    for (int q4 = 0; q4 < 64; q4 += 4) {
      float4 vd  = *(const float4*)&s_d[g][q4];
      float4 vdx = *(const float4*)&s_dx[g][q4];
      float4 vB  = *(const float4*)&s_B[n][q4];
      float dA;
      dA = exp2f(vd.x*Adn2); h = fmaf(dA, h, vdx.x*vB.x); S += vd.x;
      dA = exp2f(vd.y*Adn2); h = fmaf(dA, h, vdx.y*vB.y); S += vd.y;
      dA = exp2f(vd.z*Adn2); h = fmaf(dA, h, vdx.z*vB.z); S += vd.z;
      dA = exp2f(vd.w*Adn2); h = fmaf(dA, h, vdx.w*vB.w); S += vd.w;
    }
    __syncthreads();
  }
  int base = ((b*64 + dg)*256 + g*16 + n) + NSTATE*c;
  P[base] = exp2f(S * Adn2);
  Q[base] = h;
}

__global__ __launch_bounds__(256) void scan_stitch(
    const float* __restrict__ P, const float* __restrict__ Q,
    float* __restrict__ H)
{
  int t = blockIdx.x * 256 + threadIdx.x;   // 65536
  float h = 0.f;
  #pragma unroll
  for (int c = 0; c < NCH; ++c) {
    H[t + NSTATE*c] = h;
    h = fmaf(P[t + NSTATE*c], h, Q[t + NSTATE*c]);
  }
}

__global__ __launch_bounds__(256) void scan_p2(
    const unsigned short* __restrict__ deltab,
    const unsigned short* __restrict__ xsb,
    const unsigned short* __restrict__ xzb,   // read z half (bf16)
    const float* __restrict__ dbc,            // Bm at 32+n, Cm at 48+n
    const float* __restrict__ A_log,
    const float* __restrict__ D_skip,
    const float* __restrict__ H,
    unsigned short* __restrict__ ymulb)
{
  int blk = blockIdx.x;
  int c  = blk & (NCH-1);
  int dg = (blk >> 3) & 63;
  int b  = blk >> 9;
  int tid = threadIdx.x;
  int g = tid >> 4, n = tid & 15;
  int d0 = dg*16;
  float Adn2 = -__expf(A_log[(d0+g)*DS + n]) * 1.44269504f;
  __shared__ float s_d[16][68], s_dx[16][68], s_B[16][68], s_C[16][68];
  __shared__ float s_z[64][17], s_t[64][17];
  __shared__ float s_yp[16][16][17];   // [d][n][step] partials, padded
  float h = H[((b*64 + dg)*256 + g*16 + n) + NSTATE*c];
  int lbase = c*CHUNK;
  for (int l0 = 0; l0 < CHUNK; l0 += 64) {
    {
      int li = tid >> 2, dd = (tid & 3) * 4;
      size_t row = (size_t)b*LL + lbase + l0 + li;
      ushort4 ud = *(const ushort4*)(deltab + row*DI + d0 + dd);
      ushort4 ux = *(const ushort4*)(xsb    + row*DI + d0 + dd);
      ushort4 uz = *(const ushort4*)(xzb    + row*2*DI + DI + d0 + dd);
      float4 vB = *(const float4*)(dbc   + row*64 + 32 + dd);
      float4 vC = *(const float4*)(dbc   + row*64 + 48 + dd);
      float4 vD = *(const float4*)(D_skip + d0 + dd);
      float dx_ = b2f(ud.x), dy_ = b2f(ud.y), dz_ = b2f(ud.z), dw_ = b2f(ud.w);
      float xx_ = b2f(ux.x), xy_ = b2f(ux.y), xz2 = b2f(ux.z), xw_ = b2f(ux.w);
      float zx_ = b2f(uz.x), zy_ = b2f(uz.y), zz_ = b2f(uz.z), zw_ = b2f(uz.w);
      s_d [dd+0][li]=dx_; s_d [dd+1][li]=dy_; s_d [dd+2][li]=dz_; s_d [dd+3][li]=dw_;
      s_dx[dd+0][li]=dx_*xx_; s_dx[dd+1][li]=dy_*xy_; s_dx[dd+2][li]=dz_*xz2; s_dx[dd+3][li]=dw_*xw_;
      s_B [dd+0][li]=vB.x; s_B [dd+1][li]=vB.y; s_B [dd+2][li]=vB.z; s_B [dd+3][li]=vB.w;
      s_C [dd+0][li]=vC.x; s_C [dd+1][li]=vC.y; s_C [dd+2][li]=vC.z; s_C [dd+3][li]=vC.w;
      float szx = zx_ / (1.f + __expf(-zx_));
      float szy = zy_ / (1.f + __expf(-zy_));
      float szz = zz_ / (1.f + __expf(-zz_));
      float szw = zw_ / (1.f + __expf(-zw_));
      s_z[li][dd+0]=szx; s_z[li][dd+1]=szy; s_z[li][dd+2]=szz; s_z[li][dd+3]=szw;
      s_t[li][dd+0]=xx_*vD.x*szx; s_t[li][dd+1]=xy_*vD.y*szy;
      s_t[li][dd+2]=xz2*vD.z*szz; s_t[li][dd+3]=xw_*vD.w*szw;
    }
    __syncthreads();
    #pragma unroll
    for (int sub = 0; sub < 4; ++sub) {
      #pragma unroll
      for (int q4 = 0; q4 < 16; q4 += 4) {
        int li = sub*16 + q4;
        float4 vd  = *(const float4*)&s_d[g][li];
        float4 vdx = *(const float4*)&s_dx[g][li];
        float4 vB  = *(const float4*)&s_B[n][li];
        float4 vC  = *(const float4*)&s_C[n][li];
        float dA;
        dA = exp2f(vd.x*Adn2); h = fmaf(dA, h, vdx.x*vB.x); s_yp[g][n][q4+0] = h*vC.x;
        dA = exp2f(vd.y*Adn2); h = fmaf(dA, h, vdx.y*vB.y); s_yp[g][n][q4+1] = h*vC.y;
        dA = exp2f(vd.z*Adn2); h = fmaf(dA, h, vdx.z*vB.z); s_yp[g][n][q4+2] = h*vC.z;
        dA = exp2f(vd.w*Adn2); h = fmaf(dA, h, vdx.w*vB.w); s_yp[g][n][q4+3] = h*vC.w;
      }
      __syncthreads();
      {
        int q_r = tid & 15, g_r = tid >> 4;
        float y = 0.f;
        #pragma unroll
        for (int nn = 0; nn < 16; ++nn) y += s_yp[g_r][nn][q_r];
        int lis = sub*16 + q_r;
        float v = y * s_z[lis][g_r] + s_t[lis][g_r];
        ymulb[((size_t)b*LL + lbase + l0 + lis)*DI + d0 + g_r] = f2bf(v);
      }
      __syncthreads();
    }
  }
}

extern "C" void kernel_launch(void* const* d_in, const int* in_sizes, int n_in,
                              void* d_out, int out_size, void* d_ws, size_t ws_size,
                              hipStream_t stream) {
  const float* x         = (const float*)d_in[0];
  const float* in_proj_w = (const float*)d_in[1];
  const float* conv_w    = (const float*)d_in[2];
  const float* conv_b    = (const float*)d_in[3];
  const float* x_proj_w  = (const float*)d_in[4];
  const float* dt_proj_w = (const float*)d_in[5];
  const float* dt_proj_b = (const float*)d_in[6];
  const float* A_log     = (const float*)d_in[7];
  const float* D_skip    = (const float*)d_in[8];
  const float* out_proj_w= (const float*)d_in[9];
  const float* moe_w1    = (const float*)d_in[10];
  const float* moe_b1    = (const float*)d_in[11];
  const float* moe_w2    = (const float*)d_in[12];
  const float* moe_b2    = (const float*)d_in[13];
  float* out = (float*)d_out;

  // Arena (floats). d_ws is ~268 MB; we use ~95 MB, no overlays.
  float* p = (float*)d_ws;
  float* h1    = p; p += 2097152;            // (4096,512) f32
  float* h2    = p; p += 2097152;            // (4096,512) f32
  float* dbc   = p; p += 262144;             // (4096,64) f32
  float* Pbuf  = p; p += NSTATE*NCH/1;       // wait: NSTATE*NCH = 524288
  float* Qbuf  = p; p += 524288;
  float* Hbuf  = p; p += 524288;
  float* b2avg = p; p += 1024;
  unsigned short* h1b    = (unsigned short*)p; p += 1048576;   // 2M elems
  unsigned short* xzb    = (unsigned short*)p; p += 4194304;   // 8M elems
  unsigned short* xsb    = (unsigned short*)p; p += 2097152;   // 4M elems
  unsigned short* deltab = (unsigned short*)p; p += 2097152;   // 4M elems
  unsigned short* dbcb   = (unsigned short*)p; p += 131072;    // 256K elems
  unsigned short* ymulb  = (unsigned short*)p; p += 2097152;   // 4M elems
  unsigned short* h2lnb  = (unsigned short*)p; p += 1048576;   // 2M elems
  unsigned short* acatb  = (unsigned short*)p; p += 4194304;   // 8M elems
  unsigned short* inpb   = (unsigned short*)p; p += 524288;    // 1M elems
  unsigned short* xpjb   = (unsigned short*)p; p += 32768;
  unsigned short* dtpb   = (unsigned short*)p; p += 16384;
  unsigned short* outpb  = (unsigned short*)p; p += 262144;
  unsigned short* w1b    = (unsigned short*)p; p += 524288;
  unsigned short* w2cb   = (unsigned short*)p; p += 524288;

  // 0) fused weight prep (bf16 conversions + w2 repack + b2avg)
  prep_kernel<<<1024, 256, 0, stream>>>(in_proj_w, x_proj_w, dt_proj_w, out_proj_w,
                                        moe_w1, moe_w2, moe_b2,
                                        inpb, xpjb, dtpb, outpb, w1b, w2cb, b2avg);
  // 1) h1 = LN(x)  (fp32 + bf16)
  ln_kernel<<<MM, 256, 0, stream>>>(x, h1, h1b);
  // 2) xzb = h1 @ in_proj_w^T  (4096 x 2048, K=512) -> bf16
  gemm_mfma<128,128,64,2,2,4,4,ACT_NONE,false,true,true><<<512, 256, 0, stream>>>(
      h1b, DM, inpb, DM, nullptr, nullptr, 0, nullptr, xzb, 2*DI, DM, 1.f, 16);
  // 3) xsb = silu(causal depthwise conv(xc) + b)  (bf16 in/out)
  conv_silu_kernel<<<(MM*DI/8)/256, 256, 0, stream>>>(xzb, conv_w, conv_b, xsb);
  // 4) dbc = xs @ x_proj_w^T   (4096 x 64, K=1024)  (fp32 + bf16)
  gemm_mfma<64,64,64,2,2,2,2,ACT_NONE,true,true,true><<<64, 256, 0, stream>>>(
      xsb, DI, xpjb, DI, nullptr, nullptr, 0, dbc, dbcb, 64, DI, 1.f, 1);
  // 5) deltab = softplus(dt @ dt_proj_w^T + b)   (4096 x 1024, K=32) -> bf16
  gemm_mfma<128,128,32,2,2,4,4,ACT_SP,false,true,false><<<256, 256, 0, stream>>>(
      dbcb, 64, dtpb, DTR, dt_proj_b, nullptr, 0, nullptr, deltab, DI, DTR, 1.f, 8);
  // 6) chunked selective scan -> ymulb (bf16)
  scan_p1<<<BB*64*NCH, 256, 0, stream>>>(deltab, xsb, dbc, A_log, Pbuf, Qbuf);
  scan_stitch<<<NSTATE/256, 256, 0, stream>>>(Pbuf, Qbuf, Hbuf);
  scan_p2<<<BB*64*NCH, 256, 0, stream>>>(deltab, xsb, xzb, dbc, A_log, D_skip, Hbuf, ymulb);
  // 7) h2 = ymul @ out_proj_w^T + h1   (4096 x 512, K=1024)
  gemm_mfma<64,64,64,2,2,2,2,ACT_NONE,true,false,true><<<512, 256, 0, stream>>>(
      ymulb, DI, outpb, DI, nullptr, h1, DM, h2, nullptr, DM, DI, 1.f, 8);
  // 8) h2lnb = LN(h2) (bf16 only)
  ln_kernel<<<MM, 256, 0, stream>>>(h2, nullptr, h2lnb);
  // 9) acatb = relu(h2ln @ moe_w1cat^T + b1)   (4096 x 2048, K=512) bf16 out
  gemm_mfma<128,128,64,2,2,4,4,ACT_RELU,false,true,true><<<512, 256, 0, stream>>>(
      h2lnb, DM, w1b, DM, moe_b1, nullptr, 0, nullptr, acatb, 2*DI, DM, 1.f, 16);
  // 10) out = 0.5*(acat @ w2cat^T) + b2avg + x   (4096 x 512, K=2048)
  gemm_mfma<64,64,64,2,2,2,2,ACT_NONE,true,false,true><<<512, 256, 0, stream>>>(
      acatb, 2*DI, w2cb, 2*DI, b2avg, x, DM, out, nullptr, DM, 2*DI, 0.5f, 8);
}

// Round 8
// 210.964 us; speedup vs baseline: 5.5262x; 1.0495x over previous
//
#include <hip/hip_runtime.h>
#include <hip/hip_bf16.h>

// Sizes (match reference)
#define BB 4
#define LL 1024
#define DM 512
#define DI 1024
#define DS 16
#define DTR 32
#define MM (BB*LL)        // 4096 rows

#define ACT_NONE 0
#define ACT_RELU 1

#define CHUNK 128
#define NCH (LL/CHUNK)    // 8 chunks
#define NSTATE 65536      // B * DI * DS

typedef __attribute__((ext_vector_type(8))) __bf16 bf16x8;
typedef __attribute__((ext_vector_type(8))) unsigned short us8;
typedef __attribute__((ext_vector_type(4))) float f32x4;

__device__ __forceinline__ unsigned short f2bf(float f) {
  union { float f; unsigned int u; } a; a.f = f;
  unsigned int r = a.u + 0x7fffu + ((a.u >> 16) & 1u);
  return (unsigned short)(r >> 16);
}
__device__ __forceinline__ float b2f(unsigned short u) {
  union { unsigned int i; float f; } a; a.i = (unsigned int)u << 16; return a.f;
}

__device__ __forceinline__ bf16x8 ld_frag(const unsigned short* p) {
  us8 s = *(const us8*)p;
  return __builtin_bit_cast(bf16x8, s);
}

// async global->LDS, 16B per lane. LDS dest must be wave-uniform base + lane*16.
__device__ __forceinline__ void gload16(const void* g, void* l) {
  __builtin_amdgcn_global_load_lds(
      (const __attribute__((address_space(1))) void*)g,
      (__attribute__((address_space(3))) void*)l, 16, 0, 0);
}

// ---------------- Fused: weight prep (blocks >= MM) + LayerNorm(x) ----------
__global__ __launch_bounds__(256) void prep_ln_kernel(
    const float* __restrict__ x,
    const float* __restrict__ in_proj_w, const float* __restrict__ x_proj_w,
    const float* __restrict__ out_proj_w,
    const float* __restrict__ moe_w1,    const float* __restrict__ moe_w2,
    const float* __restrict__ moe_b2,
    float* __restrict__ h1, unsigned short* __restrict__ h1b,
    unsigned short* __restrict__ inpb,  unsigned short* __restrict__ xpjb,
    unsigned short* __restrict__ outpb,
    unsigned short* __restrict__ w1b,   unsigned short* __restrict__ w2cb,
    float* __restrict__ b2avg)
{
  __shared__ float red[8];
  int bid = blockIdx.x;
  if (bid < MM) {
    // LayerNorm row
    int row = bid;
    const float* p = x + (size_t)row * DM;
    float2 v = ((const float2*)p)[threadIdx.x];
    float s  = v.x + v.y;
    float ss = v.x*v.x + v.y*v.y;
    for (int o = 32; o; o >>= 1) { s += __shfl_down(s, o); ss += __shfl_down(ss, o); }
    int wid = threadIdx.x >> 6, lane = threadIdx.x & 63;
    if (lane == 0) { red[wid] = s; red[4+wid] = ss; }
    __syncthreads();
    s  = red[0]+red[1]+red[2]+red[3];
    ss = red[4]+red[5]+red[6]+red[7];
    float mu = s * (1.f/DM);
    float var = ss * (1.f/DM) - mu*mu;
    float rstd = rsqrtf(var + 1e-5f);
    float2 o2; o2.x = (v.x-mu)*rstd; o2.y = (v.y-mu)*rstd;
    ((float2*)(h1 + (size_t)row*DM))[threadIdx.x] = o2;
    ushort2 u; u.x = f2bf(o2.x); u.y = f2bf(o2.y);
    ((ushort2*)(h1b + (size_t)row*DM))[threadIdx.x] = u;
    return;
  }
  int i = (bid - MM) * 256 + threadIdx.x;   // 262144 threads
  int i4 = i * 4;
  auto cvt4 = [&](const float* src, unsigned short* dst) {
    float4 v = ((const float4*)src)[i];
    ushort4 o; o.x = f2bf(v.x); o.y = f2bf(v.y); o.z = f2bf(v.z); o.w = f2bf(v.w);
    ((ushort4*)dst)[i] = o;
  };
  if (i4 < 2*DI*DM) cvt4(in_proj_w, inpb);
  if (i4 < 64*DI)   cvt4(x_proj_w, xpjb);
  if (i4 < DM*DI)   cvt4(out_proj_w, outpb);
  if (i4 < 2*(2*DM)*DM) cvt4(moe_w1, w1b);
  if (i4 < DM*2*DI) {
    #pragma unroll
    for (int j = 0; j < 4; ++j) {
      int idx = i4 + j;
      int nrow = idx >> 11;
      int t = idx & (2*DI - 1);
      int e = t >> 10;
      int k = t & (DI - 1);
      w2cb[idx] = f2bf(moe_w2[((size_t)e*DM + nrow)*DI + k]);
    }
  }
  if (i4 < DM) {
    #pragma unroll
    for (int j = 0; j < 4; ++j)
      b2avg[i4+j] = 0.5f * (moe_b2[i4+j] + moe_b2[DM + i4+j]);
  }
}

// ---------------- LayerNorm (standalone, for h2) ----------------
__global__ __launch_bounds__(256) void ln_kernel(const float* __restrict__ in,
                                                 float* __restrict__ outf,
                                                 unsigned short* __restrict__ outb) {
  int row = blockIdx.x;
  const float* p = in + (size_t)row * DM;
  float2 v = ((const float2*)p)[threadIdx.x];
  float s  = v.x + v.y;
  float ss = v.x*v.x + v.y*v.y;
  for (int o = 32; o; o >>= 1) { s += __shfl_down(s, o); ss += __shfl_down(ss, o); }
  __shared__ float red[8];
  int wid = threadIdx.x >> 6, lane = threadIdx.x & 63;
  if (lane == 0) { red[wid] = s; red[4+wid] = ss; }
  __syncthreads();
  s  = red[0]+red[1]+red[2]+red[3];
  ss = red[4]+red[5]+red[6]+red[7];
  float mu = s * (1.f/DM);
  float var = ss * (1.f/DM) - mu*mu;
  float rstd = rsqrtf(var + 1e-5f);
  float2 o2; o2.x = (v.x-mu)*rstd; o2.y = (v.y-mu)*rstd;
  if (outf) ((float2*)(outf + (size_t)row*DM))[threadIdx.x] = o2;
  if (outb) {
    ushort2 u; u.x = f2bf(o2.x); u.y = f2bf(o2.y);
    ((ushort2*)(outb + (size_t)row*DM))[threadIdx.x] = u;
  }
}

// ---------------- bf16 MFMA GEMM: C = act(scale*A@B^T + bias) + res ---------
// Double-buffered LDS via global_load_lds with COUNTED vmcnt (loads stay in
// flight across raw s_barrier — no full drain). BK=64 XOR bank swizzle
// (pre-swizzled global source + swizzled ds_read, linear LDS dest).
template<int BM, int BN, int BK, int WR, int WC, int FM, int FN, int ACT,
         bool OUTF, bool OUTB>
__global__ __launch_bounds__(256) void gemm_mfma(
    const unsigned short* __restrict__ A, int lda,
    const unsigned short* __restrict__ B, int ldb,
    const float* __restrict__ bias,
    const float* __restrict__ res, int ldres,
    float* __restrict__ Cf, unsigned short* __restrict__ Cb, int ldc,
    int K, float scale, int nbx)
{
  static_assert(WR*WC == 4 && WR*FM*16 == BM && WC*FN*16 == BN, "geom");
  constexpr int ATILE = BM*BK, BTILE = BN*BK;       // elements
  constexpr int AL = ATILE/2048, BL = BTILE/2048;   // gload16 per thread
  constexpr bool SWZ = (BK == 64);
  __shared__ unsigned short As[2*ATILE];
  __shared__ unsigned short Bs[2*BTILE];
  const int tid = threadIdx.x;
  const int nwg = gridDim.x;
  const int bid = blockIdx.x;
  const int cpx = nwg >> 3;
  const int wid = ((nwg & 7) == 0) ? ((bid & 7)*cpx + (bid >> 3)) : bid;
  const int bm = (wid / nbx) * BM;
  const int bn = (wid % nbx) * BN;
  const int w = tid >> 6, lane = tid & 63;
  const int wr = w / WC, wc = w % WC;
  const int rl = lane & 15, kg = lane >> 4;

  auto stage = [&](int buf, int k0) {
    #pragma unroll
    for (int it = 0; it < AL; ++it) {
      int o = (it*256 + tid) * 16;                    // byte offset in tile
      int os = SWZ ? (o ^ (((o>>7)&7)<<4)) : o;       // source-side swizzle
      int e = os >> 1;
      int r = e / BK, c = e % BK;
      gload16(A + (size_t)(bm + r)*lda + k0 + c, (char*)As + buf*ATILE*2 + o);
    }
    #pragma unroll
    for (int it = 0; it < BL; ++it) {
      int o = (it*256 + tid) * 16;
      int os = SWZ ? (o ^ (((o>>7)&7)<<4)) : o;
      int e = os >> 1;
      int r = e / BK, c = e % BK;
      gload16(B + (size_t)(bn + r)*ldb + k0 + c, (char*)Bs + buf*BTILE*2 + o);
    }
  };

  f32x4 acc[FM][FN];
  #pragma unroll
  for (int m = 0; m < FM; ++m)
    #pragma unroll
    for (int n = 0; n < FN; ++n) { f32x4 z = {0.f,0.f,0.f,0.f}; acc[m][n] = z; }

  auto compute = [&](int buf) {
    #pragma unroll
    for (int kk = 0; kk < BK/32; ++kk) {
      bf16x8 af[FM], bfv[FN];
      #pragma unroll
      for (int m = 0; m < FM; ++m) {
        int byte = ((wr*FM*16 + m*16 + rl)*BK + kk*32 + kg*8) * 2;
        if (SWZ) byte ^= ((byte>>7)&7)<<4;
        af[m] = ld_frag((const unsigned short*)((const char*)As + buf*ATILE*2 + byte));
      }
      #pragma unroll
      for (int n = 0; n < FN; ++n) {
        int byte = ((wc*FN*16 + n*16 + rl)*BK + kk*32 + kg*8) * 2;
        if (SWZ) byte ^= ((byte>>7)&7)<<4;
        bfv[n] = ld_frag((const unsigned short*)((const char*)Bs + buf*BTILE*2 + byte));
      }
      #pragma unroll
      for (int m = 0; m < FM; ++m)
        #pragma unroll
        for (int n = 0; n < FN; ++n)
          acc[m][n] = __builtin_amdgcn_mfma_f32_16x16x32_bf16(af[m], bfv[n], acc[m][n], 0, 0, 0);
    }
  };

  stage(0, 0);
  const int nk = K / BK;
  for (int it = 0; it < nk; ++it) {
    if (it + 1 < nk) {
      stage((it&1)^1, (it+1)*BK);
      // wait for PREVIOUS tile's loads only; next tile's stay in flight
      asm volatile("s_waitcnt vmcnt(%0)" :: "i"(AL+BL) : "memory");
    } else {
      asm volatile("s_waitcnt vmcnt(0)" ::: "memory");
    }
    __builtin_amdgcn_s_barrier();          // tile (it&1) ready for all waves
    compute(it & 1);
    __builtin_amdgcn_s_barrier();          // all reads done before overwrite
  }

  // epilogue: C/D mapping col=lane&15, row=(lane>>4)*4+reg
  #pragma unroll
  for (int m = 0; m < FM; ++m) {
    int row = bm + wr*FM*16 + m*16 + kg*4;
    #pragma unroll
    for (int n = 0; n < FN; ++n) {
      int col = bn + wc*FN*16 + n*16 + rl;
      float bv = bias ? bias[col] : 0.f;
      #pragma unroll
      for (int j = 0; j < 4; ++j) {
        float v = acc[m][n][j] * scale + bv;
        if (ACT == ACT_RELU) v = fmaxf(v, 0.f);
        if (res) v += res[(size_t)(row + j)*ldres + col];
        size_t off = (size_t)(row + j)*ldc + col;
        if (OUTF) Cf[off] = v;
        if (OUTB) Cb[off] = f2bf(v);
      }
    }
  }
}

// ---------------- Depthwise causal conv (k=4) + SiLU, bf16 in/out, x8 vec ---
__global__ __launch_bounds__(256) void conv_silu_kernel(
    const unsigned short* __restrict__ xzb, const float* __restrict__ conv_w,
    const float* __restrict__ conv_b, unsigned short* __restrict__ xsb)
{
  int t = blockIdx.x * 256 + threadIdx.x;   // B*L*DI/8 = 524288
  int d8 = (t & (DI/8 - 1)) * 8;
  int l = (t >> 7) & (LL-1);
  int b = t >> 17;
  size_t base = (size_t)(b*LL) * 2*DI + d8;
  float acc[8];
  #pragma unroll
  for (int j = 0; j < 8; ++j) acc[j] = conv_b[d8+j];
  #pragma unroll
  for (int k = 0; k < 4; ++k) {
    int ll = l - 3 + k;
    if (ll >= 0) {
      us8 v = *(const us8*)(xzb + base + (size_t)ll * 2*DI);
      #pragma unroll
      for (int j = 0; j < 8; ++j)
        acc[j] = fmaf(conv_w[(d8+j)*4 + k], b2f((unsigned short)v[j]), acc[j]);
    }
  }
  us8 o;
  #pragma unroll
  for (int j = 0; j < 8; ++j) {
    float s = acc[j];
    float v = s / (1.f + __expf(-s));
    o[j] = (unsigned short)f2bf(v);
  }
  *(us8*)(xsb + (size_t)((b*LL + l)*DI) + d8) = o;
}

// ============ Chunked selective scan =========================================
// Phase 1 (fused dt_proj + softplus): per (b,dgroup,chunk) compute
// delta = softplus(dbc[:, :32] @ dtw[d,:]^T + b[d]) in-block, write deltab,
// run recurrence from h=0, emit P=exp(A*sum(delta)), Q=h_end.
__global__ __launch_bounds__(256) void scan_p1(
    const float* __restrict__ dbc,            // (B*L,64): dt 0..31, Bm 32..47
    const unsigned short* __restrict__ xsb,
    const float* __restrict__ dtw,            // (DI,32)
    const float* __restrict__ dtb,            // (DI)
    const float* __restrict__ A_log,
    float* __restrict__ P, float* __restrict__ Q,
    unsigned short* __restrict__ deltab)
{
  int blk = blockIdx.x;
  int c  = blk & (NCH-1);
  int dg = (blk >> 3) & 63;
  int b  = blk >> 9;
  int tid = threadIdx.x;
  int g = tid >> 4, n = tid & 15;
  int d0 = dg*16;
  float Adn2 = -__expf(A_log[(d0+g)*DS + n]) * 1.44269504f;
  __shared__ float s_d[16][68], s_dx[16][68], s_B[16][68];
  __shared__ float s_dt[64][33];
  __shared__ float s_w[16][32];
  __shared__ float s_bs[16];
  {
    int dr = tid >> 5, jc = tid & 31;
    s_w[dr][jc]   = dtw[(d0+dr)*DTR + jc];
    s_w[dr+8][jc] = dtw[(d0+dr+8)*DTR + jc];
    if (tid < 16) s_bs[tid] = dtb[d0 + tid];
  }
  float h = 0.f, S = 0.f;
  int lbase = c*CHUNK;
  for (int l0 = 0; l0 < CHUNK; l0 += 64) {
    {
      int li = tid >> 2, dd = (tid & 3) * 4;
      size_t row = (size_t)b*LL + lbase + l0 + li;
      ushort4 ux = *(const ushort4*)(xsb + row*DI + d0 + dd);
      float4 vB = *(const float4*)(dbc + row*64 + 32 + dd);
      float4 t0 = *(const float4*)(dbc + row*64 + dd);
      float4 t1 = *(const float4*)(dbc + row*64 + 16 + dd);
      s_dx[dd+0][li]=b2f(ux.x); s_dx[dd+1][li]=b2f(ux.y);
      s_dx[dd+2][li]=b2f(ux.z); s_dx[dd+3][li]=b2f(ux.w);
      s_B [dd+0][li]=vB.x; s_B [dd+1][li]=vB.y; s_B [dd+2][li]=vB.z; s_B [dd+3][li]=vB.w;
      *(float4*)&s_dt[li][dd]      = t0;
      *(float4*)&s_dt[li][16 + dd] = t1;
    }
    __syncthreads();
    {
      int l = tid & 63, dq = tid >> 6;
      size_t row = (size_t)b*LL + lbase + l0 + l;
      ushort4 dout;
      #pragma unroll
      for (int k = 0; k < 4; ++k) {
        int d = dq*4 + k;
        float acc = s_bs[d];
        #pragma unroll
        for (int j = 0; j < 32; j += 4) {
          float4 wt  = *(const float4*)&s_w[d][j];
          float4 dt4 = *(const float4*)&s_dt[l][j];
          acc = fmaf(wt.x, dt4.x, acc); acc = fmaf(wt.y, dt4.y, acc);
          acc = fmaf(wt.z, dt4.z, acc); acc = fmaf(wt.w, dt4.w, acc);
        }
        float sp = fmaxf(acc, 0.f) + log1pf(__expf(-fabsf(acc)));
        unsigned short spb = f2bf(sp);
        float spf = b2f(spb);              // round through bf16 to match p2
        ((unsigned short*)&dout)[k] = spb;
        s_d[d][l] = spf;
        s_dx[d][l] *= spf;                 // xs -> delta*xs in place
      }
      *(ushort4*)(deltab + row*DI + d0 + dq*4) = dout;
    }
    __syncthreads();
    #pragma unroll
    for (int q4 = 0; q4 < 64; q4 += 4) {
      float4 vd  = *(const float4*)&s_d[g][q4];
      float4 vdx = *(const float4*)&s_dx[g][q4];
      float4 vB  = *(const float4*)&s_B[n][q4];
      float dA;
      dA = exp2f(vd.x*Adn2); h = fmaf(dA, h, vdx.x*vB.x); S += vd.x;
      dA = exp2f(vd.y*Adn2); h = fmaf(dA, h, vdx.y*vB.y); S += vd.y;
      dA = exp2f(vd.z*Adn2); h = fmaf(dA, h, vdx.z*vB.z); S += vd.z;
      dA = exp2f(vd.w*Adn2); h = fmaf(dA, h, vdx.w*vB.w); S += vd.w;
    }
    __syncthreads();
  }
  int base = ((b*64 + dg)*256 + g*16 + n) + NSTATE*c;
  P[base] = exp2f(S * Adn2);
  Q[base] = h;
}

// Phase 2: stitch H inline (<=7 fmaf), re-run chunk, deferred reduction,
// fused D-skip + silu(z) tail -> bf16.
__global__ __launch_bounds__(256) void scan_p2(
    const unsigned short* __restrict__ deltab,
    const unsigned short* __restrict__ xsb,
    const unsigned short* __restrict__ xzb,   // read z half (bf16)
    const float* __restrict__ dbc,            // Bm at 32+n, Cm at 48+n
    const float* __restrict__ A_log,
    const float* __restrict__ D_skip,
    const float* __restrict__ P, const float* __restrict__ Q,
    unsigned short* __restrict__ ymulb)
{
  int blk = blockIdx.x;
  int c  = blk & (NCH-1);
  int dg = (blk >> 3) & 63;
  int b  = blk >> 9;
  int tid = threadIdx.x;
  int g = tid >> 4, n = tid & 15;
  int d0 = dg*16;
  float Adn2 = -__expf(A_log[(d0+g)*DS + n]) * 1.44269504f;
  __shared__ float s_d[16][68], s_dx[16][68], s_B[16][68], s_C[16][68];
  __shared__ float s_z[64][17], s_t[64][17];
  __shared__ float s_yp[16][16][17];   // [d][n][step] partials, padded
  // inline stitch: compose prior chunks' affine maps
  float h = 0.f;
  {
    int t = (b*64 + dg)*256 + g*16 + n;
    for (int cc = 0; cc < c; ++cc)
      h = fmaf(P[t + NSTATE*cc], h, Q[t + NSTATE*cc]);
  }
  int lbase = c*CHUNK;
  for (int l0 = 0; l0 < CHUNK; l0 += 64) {
    {
      int li = tid >> 2, dd = (tid & 3) * 4;
      size_t row = (size_t)b*LL + lbase + l0 + li;
      ushort4 ud = *(const ushort4*)(deltab + row*DI + d0 + dd);
      ushort4 ux = *(const ushort4*)(xsb    + row*DI + d0 + dd);
      ushort4 uz = *(const ushort4*)(xzb    + row*2*DI + DI + d0 + dd);
      float4 vB = *(const float4*)(dbc   + row*64 + 32 + dd);
      float4 vC = *(const float4*)(dbc   + row*64 + 48 + dd);
      float4 vD = *(const float4*)(D_skip + d0 + dd);
      float dx_ = b2f(ud.x), dy_ = b2f(ud.y), dz_ = b2f(ud.z), dw_ = b2f(ud.w);
      float xx_ = b2f(ux.x), xy_ = b2f(ux.y), xz2 = b2f(ux.z), xw_ = b2f(ux.w);
      float zx_ = b2f(uz.x), zy_ = b2f(uz.y), zz_ = b2f(uz.z), zw_ = b2f(uz.w);
      s_d [dd+0][li]=dx_; s_d [dd+1][li]=dy_; s_d [dd+2][li]=dz_; s_d [dd+3][li]=dw_;
      s_dx[dd+0][li]=dx_*xx_; s_dx[dd+1][li]=dy_*xy_; s_dx[dd+2][li]=dz_*xz2; s_dx[dd+3][li]=dw_*xw_;
      s_B [dd+0][li]=vB.x; s_B [dd+1][li]=vB.y; s_B [dd+2][li]=vB.z; s_B [dd+3][li]=vB.w;
      s_C [dd+0][li]=vC.x; s_C [dd+1][li]=vC.y; s_C [dd+2][li]=vC.z; s_C [dd+3][li]=vC.w;
      float szx = zx_ / (1.f + __expf(-zx_));
      float szy = zy_ / (1.f + __expf(-zy_));
      float szz = zz_ / (1.f + __expf(-zz_));
      float szw = zw_ / (1.f + __expf(-zw_));
      s_z[li][dd+0]=szx; s_z[li][dd+1]=szy; s_z[li][dd+2]=szz; s_z[li][dd+3]=szw;
      s_t[li][dd+0]=xx_*vD.x*szx; s_t[li][dd+1]=xy_*vD.y*szy;
      s_t[li][dd+2]=xz2*vD.z*szz; s_t[li][dd+3]=xw_*vD.w*szw;
    }
    __syncthreads();
    #pragma unroll
    for (int sub = 0; sub < 4; ++sub) {
      #pragma unroll
      for (int q4 = 0; q4 < 16; q4 += 4) {
        int li = sub*16 + q4;
        float4 vd  = *(const float4*)&s_d[g][li];
        float4 vdx = *(const float4*)&s_dx[g][li];
        float4 vB  = *(const float4*)&s_B[n][li];
        float4 vC  = *(const float4*)&s_C[n][li];
        float dA;
        dA = exp2f(vd.x*Adn2); h = fmaf(dA, h, vdx.x*vB.x); s_yp[g][n][q4+0] = h*vC.x;
        dA = exp2f(vd.y*Adn2); h = fmaf(dA, h, vdx.y*vB.y); s_yp[g][n][q4+1] = h*vC.y;
        dA = exp2f(vd.z*Adn2); h = fmaf(dA, h, vdx.z*vB.z); s_yp[g][n][q4+2] = h*vC.z;
        dA = exp2f(vd.w*Adn2); h = fmaf(dA, h, vdx.w*vB.w); s_yp[g][n][q4+3] = h*vC.w;
      }
      __syncthreads();
      {
        int q_r = tid & 15, g_r = tid >> 4;
        float y = 0.f;
        #pragma unroll
        for (int nn = 0; nn < 16; ++nn) y += s_yp[g_r][nn][q_r];
        int lis = sub*16 + q_r;
        float v = y * s_z[lis][g_r] + s_t[lis][g_r];
        ymulb[((size_t)b*LL + lbase + l0 + lis)*DI + d0 + g_r] = f2bf(v);
      }
      __syncthreads();
    }
  }
}

extern "C" void kernel_launch(void* const* d_in, const int* in_sizes, int n_in,
                              void* d_out, int out_size, void* d_ws, size_t ws_size,
                              hipStream_t stream) {
  const float* x         = (const float*)d_in[0];
  const float* in_proj_w = (const float*)d_in[1];
  const float* conv_w    = (const float*)d_in[2];
  const float* conv_b    = (const float*)d_in[3];
  const float* x_proj_w  = (const float*)d_in[4];
  const float* dt_proj_w = (const float*)d_in[5];
  const float* dt_proj_b = (const float*)d_in[6];
  const float* A_log     = (const float*)d_in[7];
  const float* D_skip    = (const float*)d_in[8];
  const float* out_proj_w= (const float*)d_in[9];
  const float* moe_w1    = (const float*)d_in[10];
  const float* moe_b1    = (const float*)d_in[11];
  const float* moe_w2    = (const float*)d_in[12];
  const float* moe_b2    = (const float*)d_in[13];
  float* out = (float*)d_out;

  // Arena (floats). d_ws ~268 MB; we use ~90 MB.
  float* p = (float*)d_ws;
  float* h1    = p; p += 2097152;            // (4096,512) f32
  float* h2    = p; p += 2097152;            // (4096,512) f32
  float* dbc   = p; p += 262144;             // (4096,64) f32
  float* Pbuf  = p; p += 524288;             // (8,65536)
  float* Qbuf  = p; p += 524288;
  float* b2avg = p; p += 1024;
  unsigned short* h1b    = (unsigned short*)p; p += 1048576;   // 2M elems
  unsigned short* xzb    = (unsigned short*)p; p += 4194304;   // 8M elems
  unsigned short* xsb    = (unsigned short*)p; p += 2097152;   // 4M elems
  unsigned short* deltab = (unsigned short*)p; p += 2097152;   // 4M elems
  unsigned short* ymulb  = (unsigned short*)p; p += 2097152;   // 4M elems
  unsigned short* h2lnb  = (unsigned short*)p; p += 1048576;   // 2M elems
  unsigned short* acatb  = (unsigned short*)p; p += 4194304;   // 8M elems
  unsigned short* inpb   = (unsigned short*)p; p += 524288;    // 1M elems
  unsigned short* xpjb   = (unsigned short*)p; p += 32768;
  unsigned short* outpb  = (unsigned short*)p; p += 262144;
  unsigned short* w1b    = (unsigned short*)p; p += 524288;
  unsigned short* w2cb   = (unsigned short*)p; p += 524288;

  // 1) fused weight prep + LN(x)
  prep_ln_kernel<<<MM + 1024, 256, 0, stream>>>(x, in_proj_w, x_proj_w, out_proj_w,
                                                moe_w1, moe_w2, moe_b2,
                                                h1, h1b, inpb, xpjb, outpb, w1b, w2cb, b2avg);
  // 2) xzb = h1 @ in_proj_w^T  (4096 x 2048, K=512) -> bf16
  gemm_mfma<128,128,64,2,2,4,4,ACT_NONE,false,true><<<512, 256, 0, stream>>>(
      h1b, DM, inpb, DM, nullptr, nullptr, 0, nullptr, xzb, 2*DI, DM, 1.f, 16);
  // 3) xsb = silu(causal depthwise conv(xc) + b)  (bf16 in/out)
  conv_silu_kernel<<<(MM*DI/8)/256, 256, 0, stream>>>(xzb, conv_w, conv_b, xsb);
  // 4) dbc = xs @ x_proj_w^T   (4096 x 64, K=1024)  f32 out
  gemm_mfma<64,64,64,2,2,2,2,ACT_NONE,true,false><<<64, 256, 0, stream>>>(
      xsb, DI, xpjb, DI, nullptr, nullptr, 0, dbc, nullptr, 64, DI, 1.f, 1);
  // 5) scan phase 1 (fused dt_proj+softplus) -> P, Q, deltab
  scan_p1<<<BB*64*NCH, 256, 0, stream>>>(dbc, xsb, dt_proj_w, dt_proj_b, A_log,
                                         Pbuf, Qbuf, deltab);
  // 6) scan phase 2 (inline stitch) -> ymulb (bf16)
  scan_p2<<<BB*64*NCH, 256, 0, stream>>>(deltab, xsb, xzb, dbc, A_log, D_skip,
                                         Pbuf, Qbuf, ymulb);
  // 7) h2 = ymul @ out_proj_w^T + h1   (4096 x 512, K=1024)
  gemm_mfma<64,64,64,2,2,2,2,ACT_NONE,true,false><<<512, 256, 0, stream>>>(
      ymulb, DI, outpb, DI, nullptr, h1, DM, h2, nullptr, DM, DI, 1.f, 8);
  // 8) h2lnb = LN(h2) (bf16 only)
  ln_kernel<<<MM, 256, 0, stream>>>(h2, nullptr, h2lnb);
  // 9) acatb = relu(h2ln @ moe_w1cat^T + b1)   (4096 x 2048, K=512) bf16 out
  gemm_mfma<128,128,64,2,2,4,4,ACT_RELU,false,true><<<512, 256, 0, stream>>>(
      h2lnb, DM, w1b, DM, moe_b1, nullptr, 0, nullptr, acatb, 2*DI, DM, 1.f, 16);
  // 10) out = 0.5*(acat @ w2cat^T) + b2avg + x   (4096 x 512, K=2048)
  gemm_mfma<64,64,64,2,2,2,2,ACT_NONE,true,false><<<512, 256, 0, stream>>>(
      acatb, 2*DI, w2cb, 2*DI, b2avg, x, DM, out, nullptr, DM, 2*DI, 0.5f, 8);
}